// Round 1
// baseline (280.722 us; speedup 1.0000x reference)
//
#include <hip/hip_runtime.h>
#include <stdint.h>

// ---------------------------------------------------------------------------
// SelfAttention: B=8,S=1024,D=1024,H=16,HD=64
//   Y{q,k,v} = X @ W^T (bf16 MFMA, fp32 acc), then flash attention.
//   Q epilogue folds scale 0.125 * log2(e) so softmax uses exp2f.
//   V is written transposed [B][D][S] so PV B-fragments are contiguous.
// ws layout (bytes):
//   [0)            Xbf : 3 * 8192*1024 bf16   (50,331,648)
//   [50331648)     Wbf : 3 * 1024*1024 bf16   ( 6,291,456)
//   [56623104)     Ybf : 3 * 8192*1024 bf16   (50,331,648)  total 106,954,752
// ---------------------------------------------------------------------------

#define B_N 8
#define S_N 1024
#define D_N 1024
#define H_N 16
#define HD_N 64
#define M_N (B_N * S_N) /* 8192 */

typedef __bf16 bfrag __attribute__((ext_vector_type(8)));
typedef float f32x4 __attribute__((ext_vector_type(4)));
typedef unsigned short u16;

__device__ __forceinline__ u16 f2bf(float f) {  // RNE fp32 -> bf16 bits
  uint32_t u = __float_as_uint(f);
  u += 0x7FFFu + ((u >> 16) & 1u);
  return (u16)(u >> 16);
}

__device__ __forceinline__ void gl_lds16(const void* g, void* l) {
  __builtin_amdgcn_global_load_lds(
      (const __attribute__((address_space(1))) uint32_t*)g,
      (__attribute__((address_space(3))) uint32_t*)l, 16, 0, 0);
}

// ---------------- fp32 -> bf16 conversion (3 arrays per launch) ------------
__global__ void cvt3(const float* __restrict__ s0, const float* __restrict__ s1,
                     const float* __restrict__ s2, u16* __restrict__ d0,
                     u16* __restrict__ d1, u16* __restrict__ d2, int n4) {
  const float* s = blockIdx.y == 0 ? s0 : (blockIdx.y == 1 ? s1 : s2);
  u16* d = blockIdx.y == 0 ? d0 : (blockIdx.y == 1 ? d1 : d2);
  int i = blockIdx.x * 256 + threadIdx.x;
  if (i < n4) {
    float4 v = ((const float4*)s)[i];
    ushort4 o;
    o.x = f2bf(v.x); o.y = f2bf(v.y); o.z = f2bf(v.z); o.w = f2bf(v.w);
    ((ushort4*)d)[i] = o;
  }
}

// ---------------- projection GEMM: Y = X @ W^T  (m97 structure) ------------
// 128x128 tile, 4 waves (2x2), BK=64, 16x16x32 bf16 MFMA, global_load_lds.
__global__ __launch_bounds__(256) void gemm_qkv(const u16* __restrict__ Xbf,
                                                const u16* __restrict__ Wbf,
                                                u16* __restrict__ Ybf) {
  const int mat = blockIdx.z;
  const u16* A = Xbf + (size_t)mat * (M_N * D_N);
  const u16* Bw = Wbf + (size_t)mat * (D_N * D_N);
  u16* Y = Ybf + (size_t)mat * (M_N * D_N);
  const int m0 = blockIdx.y * 128;
  const int n0 = blockIdx.x * 128;

  __shared__ u16 Alds[128 * 64];
  __shared__ u16 Blds[128 * 64];

  const int t = threadIdx.x;
  const int w = t >> 6, l = t & 63;
  const int lr = l & 15, lg = l >> 4;
  const int wm = w >> 1, wn = w & 1;
  const int srow = w * 32 + (l >> 3);  // base row for chunk i (adds i*8)
  const int scol = (l & 7) * 8;

  f32x4 acc[4][4];
#pragma unroll
  for (int i = 0; i < 4; ++i)
#pragma unroll
    for (int j = 0; j < 4; ++j) acc[i][j] = (f32x4){0.f, 0.f, 0.f, 0.f};

  for (int kt = 0; kt < 16; ++kt) {
    const int k0 = kt * 64;
    __syncthreads();
#pragma unroll
    for (int i = 0; i < 4; ++i) {
      const u16* ga = A + (size_t)(m0 + srow + i * 8) * D_N + (k0 + scol);
      const u16* gb = Bw + (size_t)(n0 + srow + i * 8) * D_N + (k0 + scol);
      gl_lds16(ga, Alds + (w * 4 + i) * 512);
      gl_lds16(gb, Blds + (w * 4 + i) * 512);
    }
    __syncthreads();
#pragma unroll
    for (int kk = 0; kk < 2; ++kk) {
      bfrag af[4], bfr[4];
#pragma unroll
      for (int mf = 0; mf < 4; ++mf)
        af[mf] = *(const bfrag*)(Alds + (wm * 64 + mf * 16 + lr) * 64 + kk * 32 + lg * 8);
#pragma unroll
      for (int nf = 0; nf < 4; ++nf)
        bfr[nf] = *(const bfrag*)(Blds + (wn * 64 + nf * 16 + lr) * 64 + kk * 32 + lg * 8);
#pragma unroll
      for (int mf = 0; mf < 4; ++mf)
#pragma unroll
        for (int nf = 0; nf < 4; ++nf)
          acc[mf][nf] = __builtin_amdgcn_mfma_f32_16x16x32_bf16(af[mf], bfr[nf], acc[mf][nf], 0, 0, 0);
    }
  }

  // epilogue: mat 0 (Q) scaled by 0.125*log2(e); mat 2 (V) stored transposed.
  const float alpha = (mat == 0) ? 0.18033688011112042f : 1.0f;
  if (mat < 2) {
#pragma unroll
    for (int mf = 0; mf < 4; ++mf) {
      const int rowb = m0 + wm * 64 + mf * 16 + lg * 4;
#pragma unroll
      for (int nf = 0; nf < 4; ++nf) {
        const int col = n0 + wn * 64 + nf * 16 + lr;
#pragma unroll
        for (int r = 0; r < 4; ++r)
          Y[(size_t)(rowb + r) * D_N + col] = f2bf(acc[mf][nf][r] * alpha);
      }
    }
  } else {
#pragma unroll
    for (int mf = 0; mf < 4; ++mf) {
      const int m = m0 + wm * 64 + mf * 16 + lg * 4;
      const int b = m >> 10, s = m & 1023;
#pragma unroll
      for (int nf = 0; nf < 4; ++nf) {
        const int col = n0 + wn * 64 + nf * 16 + lr;
        ushort4 pk;
        pk.x = f2bf(acc[mf][nf][0]);
        pk.y = f2bf(acc[mf][nf][1]);
        pk.z = f2bf(acc[mf][nf][2]);
        pk.w = f2bf(acc[mf][nf][3]);
        *(ushort4*)(Y + (size_t)(b * D_N + col) * S_N + s) = pk;
      }
    }
  }
}

// ---------------- flash attention ------------------------------------------
// Block = 4 waves x 32 q-rows = 128 q rows of one (b,h). KV tiles of 64.
// Q scores already include 0.125*log2(e): softmax via exp2f, fp32 state.
__global__ __launch_bounds__(256) void attn_fwd(const u16* __restrict__ Yq,
                                                const u16* __restrict__ Yk,
                                                const u16* __restrict__ Yv,
                                                float* __restrict__ out) {
  const int bid = blockIdx.x;
  const int bh = bid >> 3, qt = bid & 7;
  const int b = bh >> 4, h = bh & 15;
  const int t = threadIdx.x, w = t >> 6, l = t & 63;
  const int lr = l & 15, lg = l >> 4;

  __shared__ u16 Klds[64][72];        // [kv][hd], +8 pad -> 2-way reads
  __shared__ u16 Vlds[64][72];        // [hd][kv] (V stored transposed in ws)
  __shared__ u16 Plds[4][32][72];     // per-wave P buffer [q][kv]

  // Q fragments, kept in registers for the whole KV loop
  bfrag qf[2][2];
#pragma unroll
  for (int mf = 0; mf < 2; ++mf)
#pragma unroll
    for (int kk = 0; kk < 2; ++kk) {
      const int q = qt * 128 + w * 32 + mf * 16 + lr;
      qf[mf][kk] = *(const bfrag*)(Yq + (size_t)(b * S_N + q) * D_N + h * HD_N + kk * 32 + lg * 8);
    }

  f32x4 o[2][4];
#pragma unroll
  for (int i = 0; i < 2; ++i)
#pragma unroll
    for (int j = 0; j < 4; ++j) o[i][j] = (f32x4){0.f, 0.f, 0.f, 0.f};
  float mrow[2][4], lrow[2][4];
#pragma unroll
  for (int i = 0; i < 2; ++i)
#pragma unroll
    for (int r = 0; r < 4; ++r) { mrow[i][r] = -3.0e38f; lrow[i][r] = 0.f; }

  const int sr = t >> 3, sc = (t & 7) * 8;  // staging: row/col-chunk

  for (int kt = 0; kt < 16; ++kt) {
    const int s0 = kt * 64;
    __syncthreads();
#pragma unroll
    for (int j = 0; j < 2; ++j) {
      const int row = j * 32 + sr;
      *(bfrag*)(&Klds[row][sc]) =
          *(const bfrag*)(Yk + (size_t)(b * S_N + s0 + row) * D_N + h * HD_N + sc);
      *(bfrag*)(&Vlds[row][sc]) =
          *(const bfrag*)(Yv + (size_t)(b * D_N + h * HD_N + row) * S_N + s0 + sc);
    }
    __syncthreads();

    // S = Q K^T  (A=Q rows, B=K rows; contraction over hd)
    f32x4 scr[2][4];
#pragma unroll
    for (int i = 0; i < 2; ++i)
#pragma unroll
      for (int j = 0; j < 4; ++j) scr[i][j] = (f32x4){0.f, 0.f, 0.f, 0.f};
#pragma unroll
    for (int kk = 0; kk < 2; ++kk) {
      bfrag kf[4];
#pragma unroll
      for (int nf = 0; nf < 4; ++nf)
        kf[nf] = *(const bfrag*)(&Klds[nf * 16 + lr][kk * 32 + lg * 8]);
#pragma unroll
      for (int mf = 0; mf < 2; ++mf)
#pragma unroll
        for (int nf = 0; nf < 4; ++nf)
          scr[mf][nf] = __builtin_amdgcn_mfma_f32_16x16x32_bf16(qf[mf][kk], kf[nf], scr[mf][nf], 0, 0, 0);
    }

    // online softmax (base-2 domain); row r of a fragment lives in 16 lanes
    float corr[2][4];
#pragma unroll
    for (int mf = 0; mf < 2; ++mf) {
#pragma unroll
      for (int r = 0; r < 4; ++r) {
        float mx = fmaxf(fmaxf(scr[mf][0][r], scr[mf][1][r]),
                         fmaxf(scr[mf][2][r], scr[mf][3][r]));
        mx = fmaxf(mx, __shfl_xor(mx, 1, 64));
        mx = fmaxf(mx, __shfl_xor(mx, 2, 64));
        mx = fmaxf(mx, __shfl_xor(mx, 4, 64));
        mx = fmaxf(mx, __shfl_xor(mx, 8, 64));
        const float mold = mrow[mf][r];
        const float mnew = fmaxf(mold, mx);
        const float c = exp2f(mold - mnew);
        mrow[mf][r] = mnew;
        corr[mf][r] = c;
        float rs = 0.f;
#pragma unroll
        for (int nf = 0; nf < 4; ++nf) {
          float p = exp2f(scr[mf][nf][r] - mnew);
          scr[mf][nf][r] = p;
          rs += p;
        }
        rs += __shfl_xor(rs, 1, 64);
        rs += __shfl_xor(rs, 2, 64);
        rs += __shfl_xor(rs, 4, 64);
        rs += __shfl_xor(rs, 8, 64);
        lrow[mf][r] = lrow[mf][r] * c + rs;
      }
    }
#pragma unroll
    for (int mf = 0; mf < 2; ++mf)
#pragma unroll
      for (int nf = 0; nf < 4; ++nf)
#pragma unroll
        for (int r = 0; r < 4; ++r) o[mf][nf][r] *= corr[mf][r];

    // P -> per-wave LDS (bf16)
#pragma unroll
    for (int mf = 0; mf < 2; ++mf)
#pragma unroll
      for (int nf = 0; nf < 4; ++nf)
#pragma unroll
        for (int r = 0; r < 4; ++r)
          Plds[w][mf * 16 + lg * 4 + r][nf * 16 + lr] = f2bf(scr[mf][nf][r]);

    // O += P V   (A=P rows(q), B=V^T rows(hd); contraction over kv)
#pragma unroll
    for (int kk = 0; kk < 2; ++kk) {
      bfrag pf[2], vf[4];
#pragma unroll
      for (int mf = 0; mf < 2; ++mf)
        pf[mf] = *(const bfrag*)(&Plds[w][mf * 16 + lr][kk * 32 + lg * 8]);
#pragma unroll
      for (int nf = 0; nf < 4; ++nf)
        vf[nf] = *(const bfrag*)(&Vlds[nf * 16 + lr][kk * 32 + lg * 8]);
#pragma unroll
      for (int mf = 0; mf < 2; ++mf)
#pragma unroll
        for (int nf = 0; nf < 4; ++nf)
          o[mf][nf] = __builtin_amdgcn_mfma_f32_16x16x32_bf16(pf[mf], vf[nf], o[mf][nf], 0, 0, 0);
    }
  }

  // epilogue: normalize and store fp32 [B][S][D]
#pragma unroll
  for (int mf = 0; mf < 2; ++mf) {
#pragma unroll
    for (int r = 0; r < 4; ++r) {
      const float inv = 1.f / lrow[mf][r];
      const int q = qt * 128 + w * 32 + mf * 16 + lg * 4 + r;
#pragma unroll
      for (int nf = 0; nf < 4; ++nf)
        out[(size_t)(b * S_N + q) * D_N + h * HD_N + nf * 16 + lr] = o[mf][nf][r] * inv;
    }
  }
}

// ---------------------------------------------------------------------------
extern "C" void kernel_launch(void* const* d_in, const int* in_sizes, int n_in,
                              void* d_out, int out_size, void* d_ws, size_t ws_size,
                              hipStream_t stream) {
  const float* Qs = (const float*)d_in[0];
  const float* Ks = (const float*)d_in[1];
  const float* Vs = (const float*)d_in[2];
  const float* WQ = (const float*)d_in[3];
  const float* WK = (const float*)d_in[4];
  const float* WV = (const float*)d_in[5];
  if (ws_size < 106954752ull) return;  // need ~102 MiB scratch

  u16* Xbf = (u16*)d_ws;             // 3 * 8,388,608
  u16* Wbf = Xbf + 25165824;         // 3 * 1,048,576
  u16* Ybf = Wbf + 3145728;          // 3 * 8,388,608
  float* out = (float*)d_out;

  cvt3<<<dim3(8192, 3), 256, 0, stream>>>(Qs, Ks, Vs, Xbf, Xbf + 8388608,
                                          Xbf + 16777216, 2097152);
  cvt3<<<dim3(1024, 3), 256, 0, stream>>>(WQ, WK, WV, Wbf, Wbf + 1048576,
                                          Wbf + 2097152, 262144);
  gemm_qkv<<<dim3(8, 64, 3), 256, 0, stream>>>(Xbf, Wbf, Ybf);
  attn_fwd<<<dim3(1024), 256, 0, stream>>>(Ybf, Ybf + 8388608, Ybf + 16777216, out);
}

// Round 2
// 241.522 us; speedup vs baseline: 1.1623x; 1.1623x over previous
//
#include <hip/hip_runtime.h>
#include <stdint.h>

// ---------------------------------------------------------------------------
// SelfAttention: B=8,S=1024,D=1024,H=16,HD=64
//   Y{q,k,v} = X @ W^T (bf16 MFMA, fp32 acc), then flash attention.
//   Q epilogue folds scale 0.125 * log2(e) so softmax uses exp2f.
//   V is written transposed [B][D][S] so PV A-fragments read V^T rows.
// attn (m214-style): swapped QK^T (S^T = K x Q^T) so each lane owns one
//   q-row's scores; in-register softmax via permlane32_swap; P packed to
//   bf16 in-register (cvt_pk + permlane32_swap) feeding PV's B operand;
//   O^T accumulated so rescale/normalize are per-lane uniform.
// ws layout (bytes):
//   [0)            Xbf : 3 * 8192*1024 bf16   (50,331,648)
//   [50331648)     Wbf : 3 * 1024*1024 bf16   ( 6,291,456)
//   [56623104)     Ybf : 3 * 8192*1024 bf16   (50,331,648)  total 106,954,752
// ---------------------------------------------------------------------------

#define B_N 8
#define S_N 1024
#define D_N 1024
#define H_N 16
#define HD_N 64
#define M_N (B_N * S_N) /* 8192 */

typedef __bf16 bfrag __attribute__((ext_vector_type(8)));
typedef float f32x4 __attribute__((ext_vector_type(4)));
typedef float f32x16 __attribute__((ext_vector_type(16)));
typedef unsigned int u32;
typedef u32 u32x2 __attribute__((ext_vector_type(2)));
typedef unsigned short u16;

__device__ __forceinline__ u16 f2bf(float f) {  // RNE fp32 -> bf16 bits
  uint32_t u = __float_as_uint(f);
  u += 0x7FFFu + ((u >> 16) & 1u);
  return (u16)(u >> 16);
}

__device__ __forceinline__ void gl_lds16(const void* g, void* l) {
  __builtin_amdgcn_global_load_lds(
      (const __attribute__((address_space(1))) uint32_t*)g,
      (__attribute__((address_space(3))) uint32_t*)l, 16, 0, 0);
}

__device__ __forceinline__ u32 cvtpk(float lo, float hi) {
  u32 r;
  asm("v_cvt_pk_bf16_f32 %0, %1, %2" : "=v"(r) : "v"(lo), "v"(hi));
  return r;
}

__device__ __forceinline__ u32x2 pl32swap(u32 a, u32 b) {
#if __has_builtin(__builtin_amdgcn_permlane32_swap)
  return __builtin_amdgcn_permlane32_swap(a, b, false, false);
#else
  u32 sa = (u32)__shfl_xor((int)a, 32, 64), sb = (u32)__shfl_xor((int)b, 32, 64);
  const bool hi = (threadIdx.x & 32) != 0;
  u32x2 r;
  r[0] = hi ? sb : a;
  r[1] = hi ? b : sa;
  return r;
#endif
}

__device__ __forceinline__ float xhalf_max(float v) {
  u32x2 r = pl32swap(__float_as_uint(v), __float_as_uint(v));
  return fmaxf(__uint_as_float(r[0]), __uint_as_float(r[1]));
}
__device__ __forceinline__ float xhalf_add(float v) {
  u32x2 r = pl32swap(__float_as_uint(v), __float_as_uint(v));
  return __uint_as_float(r[0]) + __uint_as_float(r[1]);
}

// ---------------- fp32 -> bf16 conversion (3 arrays per launch) ------------
__global__ void cvt3(const float* __restrict__ s0, const float* __restrict__ s1,
                     const float* __restrict__ s2, u16* __restrict__ d0,
                     u16* __restrict__ d1, u16* __restrict__ d2, int n4) {
  const float* s = blockIdx.y == 0 ? s0 : (blockIdx.y == 1 ? s1 : s2);
  u16* d = blockIdx.y == 0 ? d0 : (blockIdx.y == 1 ? d1 : d2);
  int i = blockIdx.x * 256 + threadIdx.x;
  if (i < n4) {
    float4 v = ((const float4*)s)[i];
    ushort4 o;
    o.x = f2bf(v.x); o.y = f2bf(v.y); o.z = f2bf(v.z); o.w = f2bf(v.w);
    ((ushort4*)d)[i] = o;
  }
}

// ---------------- projection GEMM: Y = X @ W^T  (m97 structure) ------------
// 128x128 tile, 4 waves (2x2), BK=64, 16x16x32 bf16 MFMA, global_load_lds.
__global__ __launch_bounds__(256) void gemm_qkv(const u16* __restrict__ Xbf,
                                                const u16* __restrict__ Wbf,
                                                u16* __restrict__ Ybf) {
  const int mat = blockIdx.z;
  const u16* A = Xbf + (size_t)mat * (M_N * D_N);
  const u16* Bw = Wbf + (size_t)mat * (D_N * D_N);
  u16* Y = Ybf + (size_t)mat * (M_N * D_N);
  const int m0 = blockIdx.y * 128;
  const int n0 = blockIdx.x * 128;

  __shared__ u16 Alds[128 * 64];
  __shared__ u16 Blds[128 * 64];

  const int t = threadIdx.x;
  const int w = t >> 6, l = t & 63;
  const int lr = l & 15, lg = l >> 4;
  const int wm = w >> 1, wn = w & 1;
  const int srow = w * 32 + (l >> 3);  // base row for chunk i (adds i*8)
  const int scol = (l & 7) * 8;

  f32x4 acc[4][4];
#pragma unroll
  for (int i = 0; i < 4; ++i)
#pragma unroll
    for (int j = 0; j < 4; ++j) acc[i][j] = (f32x4){0.f, 0.f, 0.f, 0.f};

  for (int kt = 0; kt < 16; ++kt) {
    const int k0 = kt * 64;
    __syncthreads();
#pragma unroll
    for (int i = 0; i < 4; ++i) {
      const u16* ga = A + (size_t)(m0 + srow + i * 8) * D_N + (k0 + scol);
      const u16* gb = Bw + (size_t)(n0 + srow + i * 8) * D_N + (k0 + scol);
      gl_lds16(ga, Alds + (w * 4 + i) * 512);
      gl_lds16(gb, Blds + (w * 4 + i) * 512);
    }
    __syncthreads();
#pragma unroll
    for (int kk = 0; kk < 2; ++kk) {
      bfrag af[4], bfr[4];
#pragma unroll
      for (int mf = 0; mf < 4; ++mf)
        af[mf] = *(const bfrag*)(Alds + (wm * 64 + mf * 16 + lr) * 64 + kk * 32 + lg * 8);
#pragma unroll
      for (int nf = 0; nf < 4; ++nf)
        bfr[nf] = *(const bfrag*)(Blds + (wn * 64 + nf * 16 + lr) * 64 + kk * 32 + lg * 8);
#pragma unroll
      for (int mf = 0; mf < 4; ++mf)
#pragma unroll
        for (int nf = 0; nf < 4; ++nf)
          acc[mf][nf] = __builtin_amdgcn_mfma_f32_16x16x32_bf16(af[mf], bfr[nf], acc[mf][nf], 0, 0, 0);
    }
  }

  // epilogue: mat 0 (Q) scaled by 0.125*log2(e); mat 2 (V) stored transposed.
  const float alpha = (mat == 0) ? 0.18033688011112042f : 1.0f;
  if (mat < 2) {
#pragma unroll
    for (int mf = 0; mf < 4; ++mf) {
      const int rowb = m0 + wm * 64 + mf * 16 + lg * 4;
#pragma unroll
      for (int nf = 0; nf < 4; ++nf) {
        const int col = n0 + wn * 64 + nf * 16 + lr;
#pragma unroll
        for (int r = 0; r < 4; ++r)
          Y[(size_t)(rowb + r) * D_N + col] = f2bf(acc[mf][nf][r] * alpha);
      }
    }
  } else {
#pragma unroll
    for (int mf = 0; mf < 4; ++mf) {
      const int m = m0 + wm * 64 + mf * 16 + lg * 4;
      const int b = m >> 10, s = m & 1023;
#pragma unroll
      for (int nf = 0; nf < 4; ++nf) {
        const int col = n0 + wn * 64 + nf * 16 + lr;
        ushort4 pk;
        pk.x = f2bf(acc[mf][nf][0]);
        pk.y = f2bf(acc[mf][nf][1]);
        pk.z = f2bf(acc[mf][nf][2]);
        pk.w = f2bf(acc[mf][nf][3]);
        *(ushort4*)(Y + (size_t)(b * D_N + col) * S_N + s) = pk;
      }
    }
  }
}

// ---------------- flash attention (swapped-QK^T, in-register softmax) ------
// 4 waves/block, each wave owns 32 q rows of one (b,h). KVBLK=64.
// S^T = K x Q^T via 32x32x16 MFMA -> lane owns q = lane&31's scores.
__global__ __launch_bounds__(256) void attn_fwd(const u16* __restrict__ Yq,
                                                const u16* __restrict__ Yk,
                                                const u16* __restrict__ Yv,
                                                float* __restrict__ out) {
  const int bid = blockIdx.x;        // B*H*8 = 1024
  const int qt = bid & 7, bh = bid >> 3;
  const int b = bh >> 4, h = bh & 15;
  const int t = threadIdx.x, w = t >> 6, l = t & 63;
  const int ln = l & 31, hi = l >> 5;

  __shared__ float Olds[4][32 * 68];  // per-wave O^T->O transpose buffer

  const int qbase = qt * 128 + w * 32;

  // Q B-fragments (col q = ln, k = hd chunk): 4 chunks of hd16, registers.
  bfrag qf[4];
  {
    const u16* qp = Yq + ((size_t)(b * S_N + qbase + ln) * D_N + h * HD_N + hi * 8);
#pragma unroll
    for (int c = 0; c < 4; ++c) qf[c] = *(const bfrag*)(qp + c * 16);
  }

  const u16* kp = Yk + ((size_t)(b * S_N + ln) * D_N + h * HD_N + hi * 8);
  const u16* vp = Yv + ((size_t)(b * D_N + h * HD_N + ln) * S_N + hi * 8);

  f32x16 o0, o1;  // O^T halves: rows hd 0-31 / 32-63, cols q
#pragma unroll
  for (int r = 0; r < 16; ++r) { o0[r] = 0.f; o1[r] = 0.f; }
  float m_r = -3.0e38f, l_r = 0.f;

  // K A-fragments for tile 0 (row kv = ln + sub*32, k = hd chunk)
  bfrag kf[8];
#pragma unroll
  for (int s = 0; s < 2; ++s)
#pragma unroll
    for (int c = 0; c < 4; ++c)
      kf[s * 4 + c] = *(const bfrag*)(kp + (size_t)(s * 32) * D_N + c * 16);

  for (int kt = 0; kt < 16; ++kt) {
    // S^T = K x Q^T over hd=64: two 32-kv subtiles
    f32x16 sa, sb;
#pragma unroll
    for (int r = 0; r < 16; ++r) { sa[r] = 0.f; sb[r] = 0.f; }
#pragma unroll
    for (int c = 0; c < 4; ++c) {
      sa = __builtin_amdgcn_mfma_f32_32x32x16_bf16(kf[c], qf[c], sa, 0, 0, 0);
      sb = __builtin_amdgcn_mfma_f32_32x32x16_bf16(kf[4 + c], qf[c], sb, 0, 0, 0);
    }

    // prefetch next tile's K (latency hides under softmax+PV)
    {
      const size_t knext = (size_t)((kt < 15 ? kt + 1 : 15) * 64) * D_N;
#pragma unroll
      for (int s = 0; s < 2; ++s)
#pragma unroll
        for (int c = 0; c < 4; ++c)
          kf[s * 4 + c] = *(const bfrag*)(kp + knext + (size_t)(s * 32) * D_N + c * 16);
    }

    // V^T A-fragments for this tile (row hd = ln + half*32, k = kv chunk)
    bfrag vf[8];
#pragma unroll
    for (int hf = 0; hf < 2; ++hf)
#pragma unroll
      for (int c = 0; c < 4; ++c)
        vf[hf * 4 + c] = *(const bfrag*)(vp + (size_t)(hf * 32) * S_N + kt * 64 + c * 16);

    // ---- online softmax, fully in-lane (q = ln for both halves) ----
    float pmax = sa[0];
#pragma unroll
    for (int r = 1; r < 16; ++r) pmax = fmaxf(pmax, sa[r]);
#pragma unroll
    for (int r = 0; r < 16; ++r) pmax = fmaxf(pmax, sb[r]);
    pmax = xhalf_max(pmax);

    if (__any(pmax > m_r + 8.f)) {  // defer-max (T13)
      const float mnew = fmaxf(m_r, pmax);
      const float corr = exp2f(m_r - mnew);
#pragma unroll
      for (int r = 0; r < 16; ++r) { o0[r] *= corr; o1[r] *= corr; }
      l_r *= corr;
      m_r = mnew;
    }

    float rsum = 0.f;
#pragma unroll
    for (int r = 0; r < 16; ++r) { sa[r] = exp2f(sa[r] - m_r); rsum += sa[r]; }
#pragma unroll
    for (int r = 0; r < 16; ++r) { sb[r] = exp2f(sb[r] - m_r); rsum += sb[r]; }
    l_r += xhalf_add(rsum);

    // ---- pack P to bf16 fragments (cvt_pk + permlane32_swap) + PV ----
    // chunk c covers kv [c*16, c*16+16): c<2 from sa, else sb.
#pragma unroll
    for (int c = 0; c < 4; ++c) {
      const int bs = (c & 1) * 8;
      float p0, p1, p2, p3, p4, p5, p6, p7;
      if (c < 2) {
        p0 = sa[bs + 0]; p1 = sa[bs + 1]; p2 = sa[bs + 2]; p3 = sa[bs + 3];
        p4 = sa[bs + 4]; p5 = sa[bs + 5]; p6 = sa[bs + 6]; p7 = sa[bs + 7];
      } else {
        p0 = sb[bs + 0]; p1 = sb[bs + 1]; p2 = sb[bs + 2]; p3 = sb[bs + 3];
        p4 = sb[bs + 4]; p5 = sb[bs + 5]; p6 = sb[bs + 6]; p7 = sb[bs + 7];
      }
      const u32 x1 = cvtpk(p0, p1), x2 = cvtpk(p2, p3);
      const u32 y1 = cvtpk(p4, p5), y2 = cvtpk(p6, p7);
      const u32x2 s1 = pl32swap(x1, y1);
      const u32x2 s2 = pl32swap(x2, y2);
      union { u32 u[4]; bfrag v; } pu;
      pu.u[0] = s1[0]; pu.u[1] = s2[0]; pu.u[2] = s1[1]; pu.u[3] = s2[1];
      o0 = __builtin_amdgcn_mfma_f32_32x32x16_bf16(vf[c], pu.v, o0, 0, 0, 0);
      o1 = __builtin_amdgcn_mfma_f32_32x32x16_bf16(vf[4 + c], pu.v, o1, 0, 0, 0);
    }
  }

  // ---- epilogue: normalize, transpose O^T -> O via LDS, coalesced store ---
  const float inv = 1.f / l_r;
  float* ow = Olds[w];
#pragma unroll
  for (int g = 0; g < 4; ++g) {
    f32x4 v0, v1;
#pragma unroll
    for (int j = 0; j < 4; ++j) {
      v0[j] = o0[g * 4 + j] * inv;
      v1[j] = o1[g * 4 + j] * inv;
    }
    const int hd0 = g * 8 + hi * 4;
    *(f32x4*)(ow + ln * 68 + hd0) = v0;
    *(f32x4*)(ow + ln * 68 + 32 + hd0) = v1;
  }
  __syncthreads();
  const int qr = l >> 1, half = l & 1;
  const float* rp = ow + qr * 68 + half * 32;
  float* op = out + ((size_t)(b * S_N + qbase + qr) * D_N + h * HD_N + half * 32);
#pragma unroll
  for (int j = 0; j < 8; ++j)
    *(f32x4*)(op + j * 4) = *(const f32x4*)(rp + j * 4);
}

// ---------------------------------------------------------------------------
extern "C" void kernel_launch(void* const* d_in, const int* in_sizes, int n_in,
                              void* d_out, int out_size, void* d_ws, size_t ws_size,
                              hipStream_t stream) {
  const float* Qs = (const float*)d_in[0];
  const float* Ks = (const float*)d_in[1];
  const float* Vs = (const float*)d_in[2];
  const float* WQ = (const float*)d_in[3];
  const float* WK = (const float*)d_in[4];
  const float* WV = (const float*)d_in[5];
  if (ws_size < 106954752ull) return;  // need ~102 MiB scratch

  u16* Xbf = (u16*)d_ws;             // 3 * 8,388,608
  u16* Wbf = Xbf + 25165824;         // 3 * 1,048,576
  u16* Ybf = Wbf + 3145728;          // 3 * 8,388,608
  float* out = (float*)d_out;

  cvt3<<<dim3(8192, 3), 256, 0, stream>>>(Qs, Ks, Vs, Xbf, Xbf + 8388608,
                                          Xbf + 16777216, 2097152);
  cvt3<<<dim3(1024, 3), 256, 0, stream>>>(WQ, WK, WV, Wbf, Wbf + 1048576,
                                          Wbf + 2097152, 262144);
  gemm_qkv<<<dim3(8, 64, 3), 256, 0, stream>>>(Xbf, Wbf, Ybf);
  attn_fwd<<<dim3(1024), 256, 0, stream>>>(Ybf, Ybf + 8388608, Ybf + 16777216, out);
}

// Round 3
// 190.008 us; speedup vs baseline: 1.4774x; 1.2711x over previous
//
#include <hip/hip_runtime.h>
#include <stdint.h>

// ---------------------------------------------------------------------------
// SelfAttention: B=8,S=1024,D=1024,H=16,HD=64
//   Y{q,k,v} = X @ W^T (bf16 MFMA, fp32 acc), then flash attention.
//   Q epilogue folds scale 0.125 * log2(e) so softmax uses exp2f.
//   V is written transposed [B][D][S] so PV A-fragments read V^T rows.
// attn: swapped QK^T (S^T = K x Q^T), in-register softmax (permlane32_swap),
//   P packed via cvt_pk+permlane, O^T accumulation. Round 3: K/V tiles staged
//   in XOR-swizzled LDS (shared by 4 waves, double-buffered, global_load_lds
//   with pre-swizzled source), XCD-chunked block swizzle, tree reductions,
//   setprio around MFMA clusters.
// ws layout (bytes):
//   [0)            Xbf : 3 * 8192*1024 bf16   (50,331,648)
//   [50331648)     Wbf : 3 * 1024*1024 bf16   ( 6,291,456)
//   [56623104)     Ybf : 3 * 8192*1024 bf16   (50,331,648)  total 106,954,752
// ---------------------------------------------------------------------------

#define B_N 8
#define S_N 1024
#define D_N 1024
#define H_N 16
#define HD_N 64
#define M_N (B_N * S_N) /* 8192 */

typedef __bf16 bfrag __attribute__((ext_vector_type(8)));
typedef float f32x4 __attribute__((ext_vector_type(4)));
typedef float f32x16 __attribute__((ext_vector_type(16)));
typedef unsigned int u32;
typedef u32 u32x2 __attribute__((ext_vector_type(2)));
typedef unsigned short u16;

__device__ __forceinline__ u16 f2bf(float f) {  // RNE fp32 -> bf16 bits
  uint32_t u = __float_as_uint(f);
  u += 0x7FFFu + ((u >> 16) & 1u);
  return (u16)(u >> 16);
}

__device__ __forceinline__ void gl_lds16(const void* g, void* l) {
  __builtin_amdgcn_global_load_lds(
      (const __attribute__((address_space(1))) uint32_t*)g,
      (__attribute__((address_space(3))) uint32_t*)l, 16, 0, 0);
}

__device__ __forceinline__ u32 cvtpk(float lo, float hi) {
  u32 r;
  asm("v_cvt_pk_bf16_f32 %0, %1, %2" : "=v"(r) : "v"(lo), "v"(hi));
  return r;
}

__device__ __forceinline__ u32x2 pl32swap(u32 a, u32 b) {
#if __has_builtin(__builtin_amdgcn_permlane32_swap)
  return __builtin_amdgcn_permlane32_swap(a, b, false, false);
#else
  u32 sa = (u32)__shfl_xor((int)a, 32, 64), sb = (u32)__shfl_xor((int)b, 32, 64);
  const bool hi = (threadIdx.x & 32) != 0;
  u32x2 r;
  r[0] = hi ? sb : a;
  r[1] = hi ? b : sa;
  return r;
#endif
}

__device__ __forceinline__ float xhalf_max(float v) {
  u32x2 r = pl32swap(__float_as_uint(v), __float_as_uint(v));
  return fmaxf(__uint_as_float(r[0]), __uint_as_float(r[1]));
}
__device__ __forceinline__ float xhalf_add(float v) {
  u32x2 r = pl32swap(__float_as_uint(v), __float_as_uint(v));
  return __uint_as_float(r[0]) + __uint_as_float(r[1]);
}

// ---------------- fp32 -> bf16 conversion (3 arrays per launch) ------------
__global__ void cvt3(const float* __restrict__ s0, const float* __restrict__ s1,
                     const float* __restrict__ s2, u16* __restrict__ d0,
                     u16* __restrict__ d1, u16* __restrict__ d2, int n4) {
  const float* s = blockIdx.y == 0 ? s0 : (blockIdx.y == 1 ? s1 : s2);
  u16* d = blockIdx.y == 0 ? d0 : (blockIdx.y == 1 ? d1 : d2);
  int i = blockIdx.x * 256 + threadIdx.x;
  if (i < n4) {
    float4 v = ((const float4*)s)[i];
    ushort4 o;
    o.x = f2bf(v.x); o.y = f2bf(v.y); o.z = f2bf(v.z); o.w = f2bf(v.w);
    ((ushort4*)d)[i] = o;
  }
}

// ---------------- projection GEMM: Y = X @ W^T  (m97 structure) ------------
__global__ __launch_bounds__(256) void gemm_qkv(const u16* __restrict__ Xbf,
                                                const u16* __restrict__ Wbf,
                                                u16* __restrict__ Ybf) {
  const int mat = blockIdx.z;
  const u16* A = Xbf + (size_t)mat * (M_N * D_N);
  const u16* Bw = Wbf + (size_t)mat * (D_N * D_N);
  u16* Y = Ybf + (size_t)mat * (M_N * D_N);
  const int m0 = blockIdx.y * 128;
  const int n0 = blockIdx.x * 128;

  __shared__ u16 Alds[128 * 64];
  __shared__ u16 Blds[128 * 64];

  const int t = threadIdx.x;
  const int w = t >> 6, l = t & 63;
  const int lr = l & 15, lg = l >> 4;
  const int wm = w >> 1, wn = w & 1;
  const int srow = w * 32 + (l >> 3);
  const int scol = (l & 7) * 8;

  f32x4 acc[4][4];
#pragma unroll
  for (int i = 0; i < 4; ++i)
#pragma unroll
    for (int j = 0; j < 4; ++j) acc[i][j] = (f32x4){0.f, 0.f, 0.f, 0.f};

  for (int kt = 0; kt < 16; ++kt) {
    const int k0 = kt * 64;
    __syncthreads();
#pragma unroll
    for (int i = 0; i < 4; ++i) {
      const u16* ga = A + (size_t)(m0 + srow + i * 8) * D_N + (k0 + scol);
      const u16* gb = Bw + (size_t)(n0 + srow + i * 8) * D_N + (k0 + scol);
      gl_lds16(ga, Alds + (w * 4 + i) * 512);
      gl_lds16(gb, Blds + (w * 4 + i) * 512);
    }
    __syncthreads();
#pragma unroll
    for (int kk = 0; kk < 2; ++kk) {
      bfrag af[4], bfr[4];
#pragma unroll
      for (int mf = 0; mf < 4; ++mf)
        af[mf] = *(const bfrag*)(Alds + (wm * 64 + mf * 16 + lr) * 64 + kk * 32 + lg * 8);
#pragma unroll
      for (int nf = 0; nf < 4; ++nf)
        bfr[nf] = *(const bfrag*)(Blds + (wn * 64 + nf * 16 + lr) * 64 + kk * 32 + lg * 8);
#pragma unroll
      for (int mf = 0; mf < 4; ++mf)
#pragma unroll
        for (int nf = 0; nf < 4; ++nf)
          acc[mf][nf] = __builtin_amdgcn_mfma_f32_16x16x32_bf16(af[mf], bfr[nf], acc[mf][nf], 0, 0, 0);
    }
  }

  const float alpha = (mat == 0) ? 0.18033688011112042f : 1.0f;
  if (mat < 2) {
#pragma unroll
    for (int mf = 0; mf < 4; ++mf) {
      const int rowb = m0 + wm * 64 + mf * 16 + lg * 4;
#pragma unroll
      for (int nf = 0; nf < 4; ++nf) {
        const int col = n0 + wn * 64 + nf * 16 + lr;
#pragma unroll
        for (int r = 0; r < 4; ++r)
          Y[(size_t)(rowb + r) * D_N + col] = f2bf(acc[mf][nf][r] * alpha);
      }
    }
  } else {
#pragma unroll
    for (int mf = 0; mf < 4; ++mf) {
      const int m = m0 + wm * 64 + mf * 16 + lg * 4;
      const int b = m >> 10, s = m & 1023;
#pragma unroll
      for (int nf = 0; nf < 4; ++nf) {
        const int col = n0 + wn * 64 + nf * 16 + lr;
        ushort4 pk;
        pk.x = f2bf(acc[mf][nf][0]);
        pk.y = f2bf(acc[mf][nf][1]);
        pk.z = f2bf(acc[mf][nf][2]);
        pk.w = f2bf(acc[mf][nf][3]);
        *(ushort4*)(Y + (size_t)(b * D_N + col) * S_N + s) = pk;
      }
    }
  }
}

// ---------------- flash attention (LDS-staged K/V, swizzled) ---------------
// 4 waves/block, each wave owns 32 q rows of one (b,h). KVBLK=64.
// K/V tiles staged in LDS (shared, double-buffered, XOR st-swizzled).
union AttnSMem {
  struct { u16 K[2][4096]; u16 V[2][4096]; } st;  // 32 KB, double-buffered
  float ol[4][32 * 34];                           // epilogue transpose (17 KB)
};

__global__ __launch_bounds__(256, 4) void attn_fwd(const u16* __restrict__ Yq,
                                                   const u16* __restrict__ Yk,
                                                   const u16* __restrict__ Yv,
                                                   float* __restrict__ out) {
  // XCD-chunked work id: 1024 blocks, 8 XCDs, 128 consecutive ids per XCD
  const int bid = blockIdx.x;
  const int wid = (bid & 7) * 128 + (bid >> 3);
  const int qt = wid & 7, bh = wid >> 3;
  const int b = bh >> 4, h = bh & 15;
  const int t = threadIdx.x, w = t >> 6, l = t & 63;
  const int ln = l & 31, hi = l >> 5;

  __shared__ AttnSMem sm;

  const int qbase = qt * 128 + w * 32;

  // ---- staging constants (pre-swizzled global source, rule 21) ----
  // seg = w*64 + l (+256 for second half): LDS linear dest, global src
  // column offset = ((l&7) ^ ((l>>3)&7)) * 8 u16 elems.
  const int row0 = w * 8 + (l >> 3);
  const int srcoff = (((l & 7) ^ ((l >> 3) & 7)) << 3);
  const u16* kS0 = Yk + ((size_t)(b * S_N + row0) * D_N + h * HD_N + srcoff);
  const u16* vS0 = Yv + ((size_t)(b * D_N + h * HD_N + row0) * S_N + srcoff);

#define STAGE(buf, tt)                                                        \
  do {                                                                        \
    const u16* ka_ = kS0 + (size_t)(tt) * 64 * D_N;                           \
    const u16* va_ = vS0 + (tt) * 64;                                         \
    gl_lds16(ka_, sm.st.K[buf] + w * 512);                                    \
    gl_lds16(ka_ + (size_t)32 * D_N, sm.st.K[buf] + 2048 + w * 512);          \
    gl_lds16(va_, sm.st.V[buf] + w * 512);                                    \
    gl_lds16(va_ + (size_t)32 * S_N, sm.st.V[buf] + 2048 + w * 512);          \
  } while (0)

  // prologue: stage tile 0 into buf 0
  STAGE(0, 0);

  // Q B-fragments (col q = ln, k = hd chunk), registers for the whole loop
  bfrag qf[4];
  {
    const u16* qp = Yq + ((size_t)(b * S_N + qbase + ln) * D_N + h * HD_N + hi * 8);
#pragma unroll
    for (int c = 0; c < 4; ++c) qf[c] = *(const bfrag*)(qp + c * 16);
  }

  // swizzled per-lane column offsets (u16 units) for K/V fragment reads
  int kcol[4];
#pragma unroll
  for (int c = 0; c < 4; ++c)
    kcol[c] = (((c * 32 + hi * 16) ^ ((ln & 7) << 4)) >> 1);

  f32x16 o0, o1;  // O^T halves: rows hd 0-31 / 32-63, cols q
#pragma unroll
  for (int r = 0; r < 16; ++r) { o0[r] = 0.f; o1[r] = 0.f; }
  float m_r = -3.0e38f, l_r = 0.f;

  __syncthreads();  // tile 0 staged (drains vmcnt)

  int cur = 0;
  for (int kt = 0; kt < 16; ++kt) {
    // issue next tile's staging (lands by end-of-iteration barrier)
    if (kt < 15) STAGE(cur ^ 1, kt + 1);

    const u16* Kb = sm.st.K[cur];
    const u16* Vb = sm.st.V[cur];

    // K A-fragments (row kv = s2*32+ln, k chunk c) — swizzled ds_read_b128
    bfrag kf[8];
#pragma unroll
    for (int s2 = 0; s2 < 2; ++s2)
#pragma unroll
      for (int c = 0; c < 4; ++c)
        kf[s2 * 4 + c] = *(const bfrag*)(Kb + (s2 * 32 + ln) * 64 + kcol[c]);

    // S^T = K x Q^T over hd=64
    f32x16 sa, sb;
#pragma unroll
    for (int r = 0; r < 16; ++r) { sa[r] = 0.f; sb[r] = 0.f; }
    __builtin_amdgcn_s_setprio(1);
#pragma unroll
    for (int c = 0; c < 4; ++c) {
      sa = __builtin_amdgcn_mfma_f32_32x32x16_bf16(kf[c], qf[c], sa, 0, 0, 0);
      sb = __builtin_amdgcn_mfma_f32_32x32x16_bf16(kf[4 + c], qf[c], sb, 0, 0, 0);
    }
    __builtin_amdgcn_s_setprio(0);

    // V^T A-fragments (row hd = hf*32+ln) — issue now, latency hides under
    // softmax
    bfrag vf[8];
#pragma unroll
    for (int hf = 0; hf < 2; ++hf)
#pragma unroll
      for (int c = 0; c < 4; ++c)
        vf[hf * 4 + c] = *(const bfrag*)(Vb + (hf * 32 + ln) * 64 + kcol[c]);

    // ---- online softmax, in-lane, tree reductions ----
    float t16[16];
#pragma unroll
    for (int r = 0; r < 16; ++r) t16[r] = fmaxf(sa[r], sb[r]);
    float t8[8];
#pragma unroll
    for (int r = 0; r < 8; ++r) t8[r] = fmaxf(t16[r], t16[r + 8]);
    float t4[4];
#pragma unroll
    for (int r = 0; r < 4; ++r) t4[r] = fmaxf(t8[r], t8[r + 4]);
    float pmax = fmaxf(fmaxf(t4[0], t4[1]), fmaxf(t4[2], t4[3]));
    pmax = xhalf_max(pmax);

    if (__any(pmax > m_r + 8.f)) {  // defer-max (T13)
      const float mnew = fmaxf(m_r, pmax);
      const float corr = exp2f(m_r - mnew);
#pragma unroll
      for (int r = 0; r < 16; ++r) { o0[r] *= corr; o1[r] *= corr; }
      l_r *= corr;
      m_r = mnew;
    }

#pragma unroll
    for (int r = 0; r < 16; ++r) sa[r] = exp2f(sa[r] - m_r);
#pragma unroll
    for (int r = 0; r < 16; ++r) sb[r] = exp2f(sb[r] - m_r);
    float s16[16];
#pragma unroll
    for (int r = 0; r < 16; ++r) s16[r] = sa[r] + sb[r];
    float s8[8];
#pragma unroll
    for (int r = 0; r < 8; ++r) s8[r] = s16[r] + s16[r + 8];
    float s4[4];
#pragma unroll
    for (int r = 0; r < 4; ++r) s4[r] = s8[r] + s8[r + 4];
    float rsum = (s4[0] + s4[1]) + (s4[2] + s4[3]);
    l_r += xhalf_add(rsum);

    // ---- pack P to bf16 (cvt_pk + permlane32_swap) + PV ----
    __builtin_amdgcn_s_setprio(1);
#pragma unroll
    for (int c = 0; c < 4; ++c) {
      const int bs = (c & 1) * 8;
      float p0, p1, p2, p3, p4, p5, p6, p7;
      if (c < 2) {
        p0 = sa[bs + 0]; p1 = sa[bs + 1]; p2 = sa[bs + 2]; p3 = sa[bs + 3];
        p4 = sa[bs + 4]; p5 = sa[bs + 5]; p6 = sa[bs + 6]; p7 = sa[bs + 7];
      } else {
        p0 = sb[bs + 0]; p1 = sb[bs + 1]; p2 = sb[bs + 2]; p3 = sb[bs + 3];
        p4 = sb[bs + 4]; p5 = sb[bs + 5]; p6 = sb[bs + 6]; p7 = sb[bs + 7];
      }
      const u32 x1 = cvtpk(p0, p1), x2 = cvtpk(p2, p3);
      const u32 y1 = cvtpk(p4, p5), y2 = cvtpk(p6, p7);
      const u32x2 s1 = pl32swap(x1, y1);
      const u32x2 s2 = pl32swap(x2, y2);
      union { u32 u[4]; bfrag v; } pu;
      pu.u[0] = s1[0]; pu.u[1] = s2[0]; pu.u[2] = s1[1]; pu.u[3] = s2[1];
      o0 = __builtin_amdgcn_mfma_f32_32x32x16_bf16(vf[c], pu.v, o0, 0, 0, 0);
      o1 = __builtin_amdgcn_mfma_f32_32x32x16_bf16(vf[4 + c], pu.v, o1, 0, 0, 0);
    }
    __builtin_amdgcn_s_setprio(0);

    __syncthreads();  // drains vmcnt(0): next tile staged; frees buf[cur]
    cur ^= 1;
  }

  // ---- epilogue: normalize, transpose O^T -> O via LDS (2 half-passes) ----
  // Wave-internal only (each wave owns sm.ol[w]); LDS reused after final
  // barrier above.
  const float inv = 1.f / l_r;
  float* ow = sm.ol[w];
  const int qr = l >> 1, ch = l & 1;
  const float* rp = ow + qr * 34 + ch * 16;
  float* op = out + ((size_t)(b * S_N + qbase + qr) * D_N + h * HD_N + ch * 16);

  // pass 0: hd 0..31 (o0)
#pragma unroll
  for (int g = 0; g < 4; ++g) {
    f32x4 v;
#pragma unroll
    for (int j = 0; j < 4; ++j) v[j] = o0[g * 4 + j] * inv;
    *(f32x4*)(ow + ln * 34 + g * 8 + hi * 4) = v;
  }
  asm volatile("s_waitcnt lgkmcnt(0)" ::: "memory");
  __builtin_amdgcn_sched_barrier(0);
#pragma unroll
  for (int j = 0; j < 4; ++j)
    *(f32x4*)(op + j * 4) = *(const f32x4*)(rp + j * 4);
  asm volatile("s_waitcnt lgkmcnt(0)" ::: "memory");
  __builtin_amdgcn_sched_barrier(0);

  // pass 1: hd 32..63 (o1)
#pragma unroll
  for (int g = 0; g < 4; ++g) {
    f32x4 v;
#pragma unroll
    for (int j = 0; j < 4; ++j) v[j] = o1[g * 4 + j] * inv;
    *(f32x4*)(ow + ln * 34 + g * 8 + hi * 4) = v;
  }
  asm volatile("s_waitcnt lgkmcnt(0)" ::: "memory");
  __builtin_amdgcn_sched_barrier(0);
#pragma unroll
  for (int j = 0; j < 4; ++j)
    *(f32x4*)(op + 32 + j * 4) = *(const f32x4*)(rp + j * 4);
#undef STAGE
}

// ---------------------------------------------------------------------------
extern "C" void kernel_launch(void* const* d_in, const int* in_sizes, int n_in,
                              void* d_out, int out_size, void* d_ws, size_t ws_size,
                              hipStream_t stream) {
  const float* Qs = (const float*)d_in[0];
  const float* Ks = (const float*)d_in[1];
  const float* Vs = (const float*)d_in[2];
  const float* WQ = (const float*)d_in[3];
  const float* WK = (const float*)d_in[4];
  const float* WV = (const float*)d_in[5];
  if (ws_size < 106954752ull) return;  // need ~102 MiB scratch

  u16* Xbf = (u16*)d_ws;             // 3 * 8,388,608
  u16* Wbf = Xbf + 25165824;         // 3 * 1,048,576
  u16* Ybf = Wbf + 3145728;          // 3 * 8,388,608
  float* out = (float*)d_out;

  cvt3<<<dim3(8192, 3), 256, 0, stream>>>(Qs, Ks, Vs, Xbf, Xbf + 8388608,
                                          Xbf + 16777216, 2097152);
  cvt3<<<dim3(1024, 3), 256, 0, stream>>>(WQ, WK, WV, Wbf, Wbf + 1048576,
                                          Wbf + 2097152, 262144);
  gemm_qkv<<<dim3(8, 64, 3), 256, 0, stream>>>(Xbf, Wbf, Ybf);
  attn_fwd<<<dim3(1024), 256, 0, stream>>>(Ybf, Ybf + 8388608, Ybf + 16777216, out);
}

// Round 4
// 189.649 us; speedup vs baseline: 1.4802x; 1.0019x over previous
//
#include <hip/hip_runtime.h>
#include <stdint.h>

// ---------------------------------------------------------------------------
// SelfAttention: B=8,S=1024,D=1024,H=16,HD=64
//   Y{q,k,v} = X @ W^T (bf16 MFMA, fp32 acc), then flash attention.
//   Q epilogue folds scale 0.125 * log2(e) so softmax uses exp2f.
//   V is written transposed [B][D][S] so PV A-fragments read V^T rows.
// attn: swapped QK^T (S^T = K x Q^T), in-register softmax (permlane32_swap),
//   P packed via cvt_pk+permlane, O^T accumulation, LDS-staged K/V
//   (double-buffered, XOR-swizzled, global_load_lds), XCD-chunked blocks.
// Round 4: XCD-chunked bijective swizzle on the GEMM grid (1536 blocks,
//   192/XCD) so the 8 n-tiles sharing each 256KB A-panel land on ONE XCD's
//   L2 — kills the 3.7x A over-fetch (FETCH 199.7 MB -> ~ideal).
// ws layout (bytes):
//   [0)            Xbf : 3 * 8192*1024 bf16   (50,331,648)
//   [50331648)     Wbf : 3 * 1024*1024 bf16   ( 6,291,456)
//   [56623104)     Ybf : 3 * 8192*1024 bf16   (50,331,648)  total 106,954,752
// ---------------------------------------------------------------------------

#define B_N 8
#define S_N 1024
#define D_N 1024
#define H_N 16
#define HD_N 64
#define M_N (B_N * S_N) /* 8192 */

typedef __bf16 bfrag __attribute__((ext_vector_type(8)));
typedef float f32x4 __attribute__((ext_vector_type(4)));
typedef float f32x16 __attribute__((ext_vector_type(16)));
typedef unsigned int u32;
typedef u32 u32x2 __attribute__((ext_vector_type(2)));
typedef unsigned short u16;

__device__ __forceinline__ u16 f2bf(float f) {  // RNE fp32 -> bf16 bits
  uint32_t u = __float_as_uint(f);
  u += 0x7FFFu + ((u >> 16) & 1u);
  return (u16)(u >> 16);
}

__device__ __forceinline__ void gl_lds16(const void* g, void* l) {
  __builtin_amdgcn_global_load_lds(
      (const __attribute__((address_space(1))) uint32_t*)g,
      (__attribute__((address_space(3))) uint32_t*)l, 16, 0, 0);
}

__device__ __forceinline__ u32 cvtpk(float lo, float hi) {
  u32 r;
  asm("v_cvt_pk_bf16_f32 %0, %1, %2" : "=v"(r) : "v"(lo), "v"(hi));
  return r;
}

__device__ __forceinline__ u32x2 pl32swap(u32 a, u32 b) {
#if __has_builtin(__builtin_amdgcn_permlane32_swap)
  return __builtin_amdgcn_permlane32_swap(a, b, false, false);
#else
  u32 sa = (u32)__shfl_xor((int)a, 32, 64), sb = (u32)__shfl_xor((int)b, 32, 64);
  const bool hi = (threadIdx.x & 32) != 0;
  u32x2 r;
  r[0] = hi ? sb : a;
  r[1] = hi ? b : sa;
  return r;
#endif
}

__device__ __forceinline__ float xhalf_max(float v) {
  u32x2 r = pl32swap(__float_as_uint(v), __float_as_uint(v));
  return fmaxf(__uint_as_float(r[0]), __uint_as_float(r[1]));
}
__device__ __forceinline__ float xhalf_add(float v) {
  u32x2 r = pl32swap(__float_as_uint(v), __float_as_uint(v));
  return __uint_as_float(r[0]) + __uint_as_float(r[1]);
}

// ---------------- fp32 -> bf16 conversion (3 arrays per launch) ------------
__global__ void cvt3(const float* __restrict__ s0, const float* __restrict__ s1,
                     const float* __restrict__ s2, u16* __restrict__ d0,
                     u16* __restrict__ d1, u16* __restrict__ d2, int n4) {
  const float* s = blockIdx.y == 0 ? s0 : (blockIdx.y == 1 ? s1 : s2);
  u16* d = blockIdx.y == 0 ? d0 : (blockIdx.y == 1 ? d1 : d2);
  int i = blockIdx.x * 256 + threadIdx.x;
  if (i < n4) {
    float4 v = ((const float4*)s)[i];
    ushort4 o;
    o.x = f2bf(v.x); o.y = f2bf(v.y); o.z = f2bf(v.z); o.w = f2bf(v.w);
    ((ushort4*)d)[i] = o;
  }
}

// ---------------- projection GEMM: Y = X @ W^T  (m97 structure) ------------
// 1536 blocks, XCD-chunked: each XCD gets 192 consecutive wids = 24 A-panels
// x 8 n-tiles (A-panel reuse inside one L2) of a single matrix.
__global__ __launch_bounds__(256) void gemm_qkv(const u16* __restrict__ Xbf,
                                                const u16* __restrict__ Wbf,
                                                u16* __restrict__ Ybf) {
  const int bid = blockIdx.x;
  const int wid = (bid & 7) * 192 + (bid >> 3);  // bijective: 1536 % 8 == 0
  const int mat = wid >> 9;                      // / 512
  const int rem = wid & 511;
  const int m0 = (rem >> 3) * 128;
  const int n0 = (rem & 7) * 128;

  const u16* A = Xbf + (size_t)mat * (M_N * D_N);
  const u16* Bw = Wbf + (size_t)mat * (D_N * D_N);
  u16* Y = Ybf + (size_t)mat * (M_N * D_N);

  __shared__ u16 Alds[128 * 64];
  __shared__ u16 Blds[128 * 64];

  const int t = threadIdx.x;
  const int w = t >> 6, l = t & 63;
  const int lr = l & 15, lg = l >> 4;
  const int wm = w >> 1, wn = w & 1;
  const int srow = w * 32 + (l >> 3);
  const int scol = (l & 7) * 8;

  f32x4 acc[4][4];
#pragma unroll
  for (int i = 0; i < 4; ++i)
#pragma unroll
    for (int j = 0; j < 4; ++j) acc[i][j] = (f32x4){0.f, 0.f, 0.f, 0.f};

  for (int kt = 0; kt < 16; ++kt) {
    const int k0 = kt * 64;
    __syncthreads();
#pragma unroll
    for (int i = 0; i < 4; ++i) {
      const u16* ga = A + (size_t)(m0 + srow + i * 8) * D_N + (k0 + scol);
      const u16* gb = Bw + (size_t)(n0 + srow + i * 8) * D_N + (k0 + scol);
      gl_lds16(ga, Alds + (w * 4 + i) * 512);
      gl_lds16(gb, Blds + (w * 4 + i) * 512);
    }
    __syncthreads();
#pragma unroll
    for (int kk = 0; kk < 2; ++kk) {
      bfrag af[4], bfr[4];
#pragma unroll
      for (int mf = 0; mf < 4; ++mf)
        af[mf] = *(const bfrag*)(Alds + (wm * 64 + mf * 16 + lr) * 64 + kk * 32 + lg * 8);
#pragma unroll
      for (int nf = 0; nf < 4; ++nf)
        bfr[nf] = *(const bfrag*)(Blds + (wn * 64 + nf * 16 + lr) * 64 + kk * 32 + lg * 8);
#pragma unroll
      for (int mf = 0; mf < 4; ++mf)
#pragma unroll
        for (int nf = 0; nf < 4; ++nf)
          acc[mf][nf] = __builtin_amdgcn_mfma_f32_16x16x32_bf16(af[mf], bfr[nf], acc[mf][nf], 0, 0, 0);
    }
  }

  const float alpha = (mat == 0) ? 0.18033688011112042f : 1.0f;
  if (mat < 2) {
#pragma unroll
    for (int mf = 0; mf < 4; ++mf) {
      const int rowb = m0 + wm * 64 + mf * 16 + lg * 4;
#pragma unroll
      for (int nf = 0; nf < 4; ++nf) {
        const int col = n0 + wn * 64 + nf * 16 + lr;
#pragma unroll
        for (int r = 0; r < 4; ++r)
          Y[(size_t)(rowb + r) * D_N + col] = f2bf(acc[mf][nf][r] * alpha);
      }
    }
  } else {
#pragma unroll
    for (int mf = 0; mf < 4; ++mf) {
      const int m = m0 + wm * 64 + mf * 16 + lg * 4;
      const int b = m >> 10, s = m & 1023;
#pragma unroll
      for (int nf = 0; nf < 4; ++nf) {
        const int col = n0 + wn * 64 + nf * 16 + lr;
        ushort4 pk;
        pk.x = f2bf(acc[mf][nf][0]);
        pk.y = f2bf(acc[mf][nf][1]);
        pk.z = f2bf(acc[mf][nf][2]);
        pk.w = f2bf(acc[mf][nf][3]);
        *(ushort4*)(Y + (size_t)(b * D_N + col) * S_N + s) = pk;
      }
    }
  }
}

// ---------------- flash attention (LDS-staged K/V, swizzled) ---------------
union AttnSMem {
  struct { u16 K[2][4096]; u16 V[2][4096]; } st;  // 32 KB, double-buffered
  float ol[4][32 * 34];                           // epilogue transpose (17 KB)
};

__global__ __launch_bounds__(256, 4) void attn_fwd(const u16* __restrict__ Yq,
                                                   const u16* __restrict__ Yk,
                                                   const u16* __restrict__ Yv,
                                                   float* __restrict__ out) {
  // XCD-chunked work id: 1024 blocks, 8 XCDs, 128 consecutive ids per XCD
  const int bid = blockIdx.x;
  const int wid = (bid & 7) * 128 + (bid >> 3);
  const int qt = wid & 7, bh = wid >> 3;
  const int b = bh >> 4, h = bh & 15;
  const int t = threadIdx.x, w = t >> 6, l = t & 63;
  const int ln = l & 31, hi = l >> 5;

  __shared__ AttnSMem sm;

  const int qbase = qt * 128 + w * 32;

  // ---- staging constants (pre-swizzled global source, rule 21) ----
  const int row0 = w * 8 + (l >> 3);
  const int srcoff = (((l & 7) ^ ((l >> 3) & 7)) << 3);
  const u16* kS0 = Yk + ((size_t)(b * S_N + row0) * D_N + h * HD_N + srcoff);
  const u16* vS0 = Yv + ((size_t)(b * D_N + h * HD_N + row0) * S_N + srcoff);

#define STAGE(buf, tt)                                                        \
  do {                                                                        \
    const u16* ka_ = kS0 + (size_t)(tt) * 64 * D_N;                           \
    const u16* va_ = vS0 + (tt) * 64;                                         \
    gl_lds16(ka_, sm.st.K[buf] + w * 512);                                    \
    gl_lds16(ka_ + (size_t)32 * D_N, sm.st.K[buf] + 2048 + w * 512);          \
    gl_lds16(va_, sm.st.V[buf] + w * 512);                                    \
    gl_lds16(va_ + (size_t)32 * S_N, sm.st.V[buf] + 2048 + w * 512);          \
  } while (0)

  STAGE(0, 0);

  bfrag qf[4];
  {
    const u16* qp = Yq + ((size_t)(b * S_N + qbase + ln) * D_N + h * HD_N + hi * 8);
#pragma unroll
    for (int c = 0; c < 4; ++c) qf[c] = *(const bfrag*)(qp + c * 16);
  }

  int kcol[4];
#pragma unroll
  for (int c = 0; c < 4; ++c)
    kcol[c] = (((c * 32 + hi * 16) ^ ((ln & 7) << 4)) >> 1);

  f32x16 o0, o1;
#pragma unroll
  for (int r = 0; r < 16; ++r) { o0[r] = 0.f; o1[r] = 0.f; }
  float m_r = -3.0e38f, l_r = 0.f;

  __syncthreads();  // tile 0 staged (drains vmcnt)

  int cur = 0;
  for (int kt = 0; kt < 16; ++kt) {
    if (kt < 15) STAGE(cur ^ 1, kt + 1);

    const u16* Kb = sm.st.K[cur];
    const u16* Vb = sm.st.V[cur];

    bfrag kf[8];
#pragma unroll
    for (int s2 = 0; s2 < 2; ++s2)
#pragma unroll
      for (int c = 0; c < 4; ++c)
        kf[s2 * 4 + c] = *(const bfrag*)(Kb + (s2 * 32 + ln) * 64 + kcol[c]);

    f32x16 sa, sb;
#pragma unroll
    for (int r = 0; r < 16; ++r) { sa[r] = 0.f; sb[r] = 0.f; }
    __builtin_amdgcn_s_setprio(1);
#pragma unroll
    for (int c = 0; c < 4; ++c) {
      sa = __builtin_amdgcn_mfma_f32_32x32x16_bf16(kf[c], qf[c], sa, 0, 0, 0);
      sb = __builtin_amdgcn_mfma_f32_32x32x16_bf16(kf[4 + c], qf[c], sb, 0, 0, 0);
    }
    __builtin_amdgcn_s_setprio(0);

    bfrag vf[8];
#pragma unroll
    for (int hf = 0; hf < 2; ++hf)
#pragma unroll
      for (int c = 0; c < 4; ++c)
        vf[hf * 4 + c] = *(const bfrag*)(Vb + (hf * 32 + ln) * 64 + kcol[c]);

    // ---- online softmax, in-lane, tree reductions ----
    float t16[16];
#pragma unroll
    for (int r = 0; r < 16; ++r) t16[r] = fmaxf(sa[r], sb[r]);
    float t8[8];
#pragma unroll
    for (int r = 0; r < 8; ++r) t8[r] = fmaxf(t16[r], t16[r + 8]);
    float t4[4];
#pragma unroll
    for (int r = 0; r < 4; ++r) t4[r] = fmaxf(t8[r], t8[r + 4]);
    float pmax = fmaxf(fmaxf(t4[0], t4[1]), fmaxf(t4[2], t4[3]));
    pmax = xhalf_max(pmax);

    if (__any(pmax > m_r + 8.f)) {  // defer-max (T13)
      const float mnew = fmaxf(m_r, pmax);
      const float corr = exp2f(m_r - mnew);
#pragma unroll
      for (int r = 0; r < 16; ++r) { o0[r] *= corr; o1[r] *= corr; }
      l_r *= corr;
      m_r = mnew;
    }

#pragma unroll
    for (int r = 0; r < 16; ++r) sa[r] = exp2f(sa[r] - m_r);
#pragma unroll
    for (int r = 0; r < 16; ++r) sb[r] = exp2f(sb[r] - m_r);
    float s16[16];
#pragma unroll
    for (int r = 0; r < 16; ++r) s16[r] = sa[r] + sb[r];
    float s8[8];
#pragma unroll
    for (int r = 0; r < 8; ++r) s8[r] = s16[r] + s16[r + 8];
    float s4[4];
#pragma unroll
    for (int r = 0; r < 4; ++r) s4[r] = s8[r] + s8[r + 4];
    float rsum = (s4[0] + s4[1]) + (s4[2] + s4[3]);
    l_r += xhalf_add(rsum);

    // ---- pack P to bf16 (cvt_pk + permlane32_swap) + PV ----
    __builtin_amdgcn_s_setprio(1);
#pragma unroll
    for (int c = 0; c < 4; ++c) {
      const int bs = (c & 1) * 8;
      float p0, p1, p2, p3, p4, p5, p6, p7;
      if (c < 2) {
        p0 = sa[bs + 0]; p1 = sa[bs + 1]; p2 = sa[bs + 2]; p3 = sa[bs + 3];
        p4 = sa[bs + 4]; p5 = sa[bs + 5]; p6 = sa[bs + 6]; p7 = sa[bs + 7];
      } else {
        p0 = sb[bs + 0]; p1 = sb[bs + 1]; p2 = sb[bs + 2]; p3 = sb[bs + 3];
        p4 = sb[bs + 4]; p5 = sb[bs + 5]; p6 = sb[bs + 6]; p7 = sb[bs + 7];
      }
      const u32 x1 = cvtpk(p0, p1), x2 = cvtpk(p2, p3);
      const u32 y1 = cvtpk(p4, p5), y2 = cvtpk(p6, p7);
      const u32x2 s1 = pl32swap(x1, y1);
      const u32x2 s2 = pl32swap(x2, y2);
      union { u32 u[4]; bfrag v; } pu;
      pu.u[0] = s1[0]; pu.u[1] = s2[0]; pu.u[2] = s1[1]; pu.u[3] = s2[1];
      o0 = __builtin_amdgcn_mfma_f32_32x32x16_bf16(vf[c], pu.v, o0, 0, 0, 0);
      o1 = __builtin_amdgcn_mfma_f32_32x32x16_bf16(vf[4 + c], pu.v, o1, 0, 0, 0);
    }
    __builtin_amdgcn_s_setprio(0);

    __syncthreads();  // drains vmcnt(0): next tile staged; frees buf[cur]
    cur ^= 1;
  }

  // ---- epilogue: normalize, transpose O^T -> O via LDS (2 half-passes) ----
  const float inv = 1.f / l_r;
  float* ow = sm.ol[w];
  const int qr = l >> 1, ch = l & 1;
  const float* rp = ow + qr * 34 + ch * 16;
  float* op = out + ((size_t)(b * S_N + qbase + qr) * D_N + h * HD_N + ch * 16);

#pragma unroll
  for (int g = 0; g < 4; ++g) {
    f32x4 v;
#pragma unroll
    for (int j = 0; j < 4; ++j) v[j] = o0[g * 4 + j] * inv;
    *(f32x4*)(ow + ln * 34 + g * 8 + hi * 4) = v;
  }
  asm volatile("s_waitcnt lgkmcnt(0)" ::: "memory");
  __builtin_amdgcn_sched_barrier(0);
#pragma unroll
  for (int j = 0; j < 4; ++j)
    *(f32x4*)(op + j * 4) = *(const f32x4*)(rp + j * 4);
  asm volatile("s_waitcnt lgkmcnt(0)" ::: "memory");
  __builtin_amdgcn_sched_barrier(0);

#pragma unroll
  for (int g = 0; g < 4; ++g) {
    f32x4 v;
#pragma unroll
    for (int j = 0; j < 4; ++j) v[j] = o1[g * 4 + j] * inv;
    *(f32x4*)(ow + ln * 34 + g * 8 + hi * 4) = v;
  }
  asm volatile("s_waitcnt lgkmcnt(0)" ::: "memory");
  __builtin_amdgcn_sched_barrier(0);
#pragma unroll
  for (int j = 0; j < 4; ++j)
    *(f32x4*)(op + 32 + j * 4) = *(const f32x4*)(rp + j * 4);
#undef STAGE
}

// ---------------------------------------------------------------------------
extern "C" void kernel_launch(void* const* d_in, const int* in_sizes, int n_in,
                              void* d_out, int out_size, void* d_ws, size_t ws_size,
                              hipStream_t stream) {
  const float* Qs = (const float*)d_in[0];
  const float* Ks = (const float*)d_in[1];
  const float* Vs = (const float*)d_in[2];
  const float* WQ = (const float*)d_in[3];
  const float* WK = (const float*)d_in[4];
  const float* WV = (const float*)d_in[5];
  if (ws_size < 106954752ull) return;  // need ~102 MiB scratch

  u16* Xbf = (u16*)d_ws;             // 3 * 8,388,608
  u16* Wbf = Xbf + 25165824;         // 3 * 1,048,576
  u16* Ybf = Wbf + 3145728;          // 3 * 8,388,608
  float* out = (float*)d_out;

  cvt3<<<dim3(8192, 3), 256, 0, stream>>>(Qs, Ks, Vs, Xbf, Xbf + 8388608,
                                          Xbf + 16777216, 2097152);
  cvt3<<<dim3(1024, 3), 256, 0, stream>>>(WQ, WK, WV, Wbf, Wbf + 1048576,
                                          Wbf + 2097152, 262144);
  gemm_qkv<<<dim3(1536), 256, 0, stream>>>(Xbf, Wbf, Ybf);
  attn_fwd<<<dim3(1024), 256, 0, stream>>>(Ybf, Ybf + 8388608, Ybf + 16777216, out);
}

// Round 5
// 179.985 us; speedup vs baseline: 1.5597x; 1.0537x over previous
//
#include <hip/hip_runtime.h>
#include <stdint.h>

// ---------------------------------------------------------------------------
// SelfAttention: B=8,S=1024,D=1024,H=16,HD=64
//   Y{q,k,v} = X @ W^T (bf16 MFMA, fp32 acc), then flash attention.
//   Q epilogue folds scale 0.125 * log2(e) so softmax uses exp2f.
//   V is written transposed [B][D][S] so PV A-fragments read V^T rows.
// Round 5: gemm_qkv rebuilt on the 256^2 8-phase template (T2+T3+T4+T5):
//   8 waves, BK=64, 128 KiB LDS (2 dbuf x {A,B} x 4 chunks of 64x64),
//   chunk-granular staging spread across phases, counted vmcnt(4) at
//   phases 4/8 only, raw s_barrier (no implicit drains), XOR-swizzled LDS
//   both-sides (stage source pre-swizzled, ds_read swizzled), setprio
//   around MFMA clusters, XCD-chunked grid.
// ws layout (bytes):
//   [0)            Xbf : 3 * 8192*1024 bf16   (50,331,648)
//   [50331648)     Wbf : 3 * 1024*1024 bf16   ( 6,291,456)
//   [56623104)     Ybf : 3 * 8192*1024 bf16   (50,331,648)  total 106,954,752
// ---------------------------------------------------------------------------

#define B_N 8
#define S_N 1024
#define D_N 1024
#define H_N 16
#define HD_N 64
#define M_N (B_N * S_N) /* 8192 */

typedef __bf16 bfrag __attribute__((ext_vector_type(8)));
typedef float f32x4 __attribute__((ext_vector_type(4)));
typedef float f32x16 __attribute__((ext_vector_type(16)));
typedef unsigned int u32;
typedef u32 u32x2 __attribute__((ext_vector_type(2)));
typedef unsigned short u16;

__device__ __forceinline__ u16 f2bf(float f) {  // RNE fp32 -> bf16 bits
  uint32_t u = __float_as_uint(f);
  u += 0x7FFFu + ((u >> 16) & 1u);
  return (u16)(u >> 16);
}

__device__ __forceinline__ void gl_lds16(const void* g, void* l) {
  __builtin_amdgcn_global_load_lds(
      (const __attribute__((address_space(1))) uint32_t*)g,
      (__attribute__((address_space(3))) uint32_t*)l, 16, 0, 0);
}

__device__ __forceinline__ u32 cvtpk(float lo, float hi) {
  u32 r;
  asm("v_cvt_pk_bf16_f32 %0, %1, %2" : "=v"(r) : "v"(lo), "v"(hi));
  return r;
}

__device__ __forceinline__ u32x2 pl32swap(u32 a, u32 b) {
#if __has_builtin(__builtin_amdgcn_permlane32_swap)
  return __builtin_amdgcn_permlane32_swap(a, b, false, false);
#else
  u32 sa = (u32)__shfl_xor((int)a, 32, 64), sb = (u32)__shfl_xor((int)b, 32, 64);
  const bool hi = (threadIdx.x & 32) != 0;
  u32x2 r;
  r[0] = hi ? sb : a;
  r[1] = hi ? b : sa;
  return r;
#endif
}

__device__ __forceinline__ float xhalf_max(float v) {
  u32x2 r = pl32swap(__float_as_uint(v), __float_as_uint(v));
  return fmaxf(__uint_as_float(r[0]), __uint_as_float(r[1]));
}
__device__ __forceinline__ float xhalf_add(float v) {
  u32x2 r = pl32swap(__float_as_uint(v), __float_as_uint(v));
  return __uint_as_float(r[0]) + __uint_as_float(r[1]);
}

// ---------------- fp32 -> bf16 conversion (3 arrays per launch) ------------
__global__ void cvt3(const float* __restrict__ s0, const float* __restrict__ s1,
                     const float* __restrict__ s2, u16* __restrict__ d0,
                     u16* __restrict__ d1, u16* __restrict__ d2, int n4) {
  const float* s = blockIdx.y == 0 ? s0 : (blockIdx.y == 1 ? s1 : s2);
  u16* d = blockIdx.y == 0 ? d0 : (blockIdx.y == 1 ? d1 : d2);
  int i = blockIdx.x * 256 + threadIdx.x;
  if (i < n4) {
    float4 v = ((const float4*)s)[i];
    ushort4 o;
    o.x = f2bf(v.x); o.y = f2bf(v.y); o.z = f2bf(v.z); o.w = f2bf(v.w);
    ((ushort4*)d)[i] = o;
  }
}

// ---------------- projection GEMM: 256^2 8-phase (m201-style) --------------
// Waves: wm = w>>2 (m half: 128 rows), wn = w&3 (n quarter: 64 cols).
// A chunks [qm][ha]: global rows m0 + ha*128 + qm*64 .. +64.
// B chunks [qn][hb]: LDS row_loc -> out col n0 + hb*128 + (row_loc>>5)*64
//   + qn*32 + (row_loc&31).
// Phase schedule per iteration (tiles T0=2it in dbuf0, T1=2it+1 in dbuf1):
//   P1: q(0,0)@d0  stage T1:A1,B0 -> d1   (4)
//   P2: q(0,1)@d0
//   P3: q(1,1)@d0  stage T0+2:A0 -> d0    (2)
//   P4: q(1,0)@d0  stage T0+2:B1 -> d0    (2)  vmcnt(4)
//   P5: q(0,0)@d1  stage T0+2:A1,B0 -> d0 (4)
//   P6: q(0,1)@d1
//   P7: q(1,1)@d1  stage T1+2:A0 -> d1    (2)
//   P8: q(1,0)@d1  stage T1+2:B1 -> d1    (2)  vmcnt(4)
// Every stage lands >=3 phases before its first read (vmcnt(4)-verified);
// every stage destination freed >=1 full phase earlier (ds_reads complete
// before each wave's barrier2 via the lgkmcnt before MFMA).
__global__ __launch_bounds__(512, 2) void gemm_qkv(const u16* __restrict__ Xbf,
                                                   const u16* __restrict__ Wbf,
                                                   u16* __restrict__ Ybf) {
  const int bid = blockIdx.x;
  const int wid = (bid & 7) * 48 + (bid >> 3);  // bijective: 384 % 8 == 0
  const int mat = wid >> 7;
  const int rem = wid & 127;
  const int m0 = (rem >> 2) * 256;
  const int n0 = (rem & 3) * 256;

  const u16* A = Xbf + (size_t)mat * (M_N * D_N);
  const u16* Bw = Wbf + (size_t)mat * (D_N * D_N);
  u16* Y = Ybf + (size_t)mat * (M_N * D_N);

  __shared__ u16 Ast[2][4][4096];  // [dbuf][qm*2+ha][64x64], 64 KB
  __shared__ u16 Bst[2][4][4096];  // [dbuf][qn*2+hb][64x64], 64 KB

  const int t = threadIdx.x;
  const int w = t >> 6, l = t & 63;
  const int lr = l & 15, lg = l >> 4;
  const int wm = w >> 2, wn = w & 3;
  const int hb = wn >> 1;

  // staging source bases (per thread); dest row_loc = t>>3, col slot t&7,
  // source col pre-swizzled so the swizzled ds_read sees linear data.
  const int swcol = (((t & 7) ^ ((t >> 3) & 7)) << 3);
  const u16* aSrc = A + (size_t)(m0 + (t >> 3)) * D_N + swcol;
  const u16* bSrc =
      Bw + (size_t)(n0 + (t >> 8) * 64 + ((t >> 3) & 31)) * D_N + swcol;

  // swizzled ds_read column offsets
  const int asw = (lr & 7) << 3;
  const int aoff0 = (lg * 8) ^ asw;
  const int aoff1 = (32 + lg * 8) ^ asw;
  const int brow = ((wn & 1) * 32 + lr) * 64;

#define STA(d, qm_, ha_, tt)                                                  \
  gl_lds16(aSrc + (size_t)((ha_)*128 + (qm_)*64) * D_N + (tt)*64,             \
           &Ast[d][(qm_)*2 + (ha_)][w * 512])
#define STB(d, qn_, hb_, tt)                                                  \
  gl_lds16(bSrc + (size_t)((hb_)*128 + (qn_)*32) * D_N + (tt)*64,             \
           &Bst[d][(qn_)*2 + (hb_)][w * 512])
#define LDA(AR, D, QM)                                                        \
  do {                                                                        \
    const u16* p_ = &Ast[D][(QM)*2 + wm][lr * 64];                            \
    AR[0][0] = *(const bfrag*)(p_ + aoff0);                                   \
    AR[0][1] = *(const bfrag*)(p_ + aoff1);                                   \
    AR[1][0] = *(const bfrag*)(p_ + 1024 + aoff0);                            \
    AR[1][1] = *(const bfrag*)(p_ + 1024 + aoff1);                            \
    AR[2][0] = *(const bfrag*)(p_ + 2048 + aoff0);                            \
    AR[2][1] = *(const bfrag*)(p_ + 2048 + aoff1);                            \
    AR[3][0] = *(const bfrag*)(p_ + 3072 + aoff0);                            \
    AR[3][1] = *(const bfrag*)(p_ + 3072 + aoff1);                            \
  } while (0)
#define LDB(BR, D, QN)                                                        \
  do {                                                                        \
    const u16* p_ = &Bst[D][(QN)*2 + hb][brow];                               \
    BR[0][0] = *(const bfrag*)(p_ + aoff0);                                   \
    BR[0][1] = *(const bfrag*)(p_ + aoff1);                                   \
    BR[1][0] = *(const bfrag*)(p_ + 1024 + aoff0);                            \
    BR[1][1] = *(const bfrag*)(p_ + 1024 + aoff1);                            \
  } while (0)
#define MMA(QM, QN, AR, BR)                                                   \
  do {                                                                        \
    __builtin_amdgcn_s_setprio(1);                                            \
    _Pragma("unroll") for (int mf_ = 0; mf_ < 4; ++mf_)                       \
    _Pragma("unroll") for (int j_ = 0; j_ < 2; ++j_)                          \
    _Pragma("unroll") for (int kk_ = 0; kk_ < 2; ++kk_)                       \
      acc[(QM)*4 + mf_][(QN)*2 + j_] =                                        \
          __builtin_amdgcn_mfma_f32_16x16x32_bf16(                            \
              AR[mf_][kk_], BR[j_][kk_], acc[(QM)*4 + mf_][(QN)*2 + j_],      \
              0, 0, 0);                                                       \
    __builtin_amdgcn_s_setprio(0);                                            \
  } while (0)
#define BARR()                                                                \
  __builtin_amdgcn_s_barrier();                                               \
  __builtin_amdgcn_sched_barrier(0)
#define WAITL()                                                               \
  asm volatile("s_waitcnt lgkmcnt(0)" ::: "memory");                          \
  __builtin_amdgcn_sched_barrier(0)
#define WAITV4()                                                              \
  asm volatile("s_waitcnt vmcnt(4)" ::: "memory");                            \
  __builtin_amdgcn_sched_barrier(0)

  f32x4 acc[8][4];
#pragma unroll
  for (int i = 0; i < 8; ++i)
#pragma unroll
    for (int j = 0; j < 4; ++j) acc[i][j] = (f32x4){0.f, 0.f, 0.f, 0.f};

  // prologue: tile0 full -> dbuf0; tile1 {A0, B1} -> dbuf1 (A1,B0 at P1)
  STA(0, 0, 0, 0); STA(0, 0, 1, 0); STA(0, 1, 0, 0); STA(0, 1, 1, 0);
  STB(0, 0, 0, 0); STB(0, 0, 1, 0); STB(0, 1, 0, 0); STB(0, 1, 1, 0);
  STA(1, 0, 0, 1); STA(1, 0, 1, 1); STB(1, 1, 0, 1); STB(1, 1, 1, 1);
  WAITV4();  // tile0's 8 landed; tile1's 4 still in flight
  BARR();

  bfrag a[4][2], a2[4][2], b0[2][2], b1[2][2];

  for (int it = 0; it < 8; ++it) {
    const int T1 = 2 * it + 1, TN = 2 * it + 2;
    const bool st = (it < 7);
    // ---- P1: q(0,0) on dbuf0; stage T1's A1,B0 -> dbuf1
    LDA(a, 0, 0);
    LDB(b0, 0, 0);
    STA(1, 1, 0, T1); STA(1, 1, 1, T1); STB(1, 0, 0, T1); STB(1, 0, 1, T1);
    BARR(); WAITL();
    MMA(0, 0, a, b0);
    BARR();
    // ---- P2: q(0,1)
    LDB(b1, 0, 1);
    BARR(); WAITL();
    MMA(0, 1, a, b1);
    BARR();
    // ---- P3: q(1,1); stage TN's A0 -> dbuf0
    LDA(a2, 0, 1);
    if (st) { STA(0, 0, 0, TN); STA(0, 0, 1, TN); }
    BARR(); WAITL();
    MMA(1, 1, a2, b1);
    BARR();
    // ---- P4: q(1,0); stage TN's B1 -> dbuf0; counted vmcnt
    if (st) { STB(0, 1, 0, TN); STB(0, 1, 1, TN); }
    BARR();
    MMA(1, 0, a2, b0);
    WAITV4();
    BARR();
    // ---- P5: q(0,0) on dbuf1; stage TN's A1,B0 -> dbuf0
    LDA(a, 1, 0);
    LDB(b0, 1, 0);
    if (st) { STA(0, 1, 0, TN); STA(0, 1, 1, TN); STB(0, 0, 0, TN); STB(0, 0, 1, TN); }
    BARR(); WAITL();
    MMA(0, 0, a, b0);
    BARR();
    // ---- P6: q(0,1)
    LDB(b1, 1, 1);
    BARR(); WAITL();
    MMA(0, 1, a, b1);
    BARR();
    // ---- P7: q(1,1); stage (TN+1)'s A0 -> dbuf1
    LDA(a2, 1, 1);
    if (st) { STA(1, 0, 0, TN + 1); STA(1, 0, 1, TN + 1); }
    BARR(); WAITL();
    MMA(1, 1, a2, b1);
    BARR();
    // ---- P8: q(1,0); stage (TN+1)'s B1 -> dbuf1; counted vmcnt
    if (st) { STB(1, 1, 0, TN + 1); STB(1, 1, 1, TN + 1); }
    BARR();
    MMA(1, 0, a2, b0);
    WAITV4();
    BARR();
  }

  // ---- epilogue ----
  const float alpha = (mat == 0) ? 0.18033688011112042f : 1.0f;
  const int mrow = m0 + wm * 128;
  const int ncol = n0 + (wn >> 1) * 128 + (wn & 1) * 64;
  if (mat < 2) {
#pragma unroll
    for (int qm = 0; qm < 2; ++qm)
#pragma unroll
      for (int mf = 0; mf < 4; ++mf)
#pragma unroll
        for (int qn = 0; qn < 2; ++qn)
#pragma unroll
          for (int j = 0; j < 2; ++j) {
            const int row0 = mrow + qm * 64 + mf * 16 + lg * 4;
            const int col = ncol + qn * 32 + j * 16 + lr;
#pragma unroll
            for (int r = 0; r < 4; ++r)
              Y[(size_t)(row0 + r) * D_N + col] =
                  f2bf(acc[qm * 4 + mf][qn * 2 + j][r] * alpha);
          }
  } else {
    const int b = m0 >> 10;
    const int sbase = (m0 & 1023) + wm * 128;
#pragma unroll
    for (int qm = 0; qm < 2; ++qm)
#pragma unroll
      for (int mf = 0; mf < 4; ++mf)
#pragma unroll
        for (int qn = 0; qn < 2; ++qn)
#pragma unroll
          for (int j = 0; j < 2; ++j) {
            const int s0 = sbase + qm * 64 + mf * 16 + lg * 4;
            const int col = ncol + qn * 32 + j * 16 + lr;
            const f32x4 v = acc[qm * 4 + mf][qn * 2 + j];
            ushort4 pk;
            pk.x = f2bf(v[0]); pk.y = f2bf(v[1]);
            pk.z = f2bf(v[2]); pk.w = f2bf(v[3]);
            *(ushort4*)(Y + (size_t)(b * D_N + col) * S_N + s0) = pk;
          }
  }
#undef STA
#undef STB
#undef LDA
#undef LDB
#undef MMA
#undef BARR
#undef WAITL
#undef WAITV4
}

// ---------------- flash attention (LDS-staged K/V, swizzled) ---------------
union AttnSMem {
  struct { u16 K[2][4096]; u16 V[2][4096]; } st;  // 32 KB, double-buffered
  float ol[4][32 * 34];                           // epilogue transpose (17 KB)
};

__global__ __launch_bounds__(256, 4) void attn_fwd(const u16* __restrict__ Yq,
                                                   const u16* __restrict__ Yk,
                                                   const u16* __restrict__ Yv,
                                                   float* __restrict__ out) {
  // XCD-chunked work id: 1024 blocks, 8 XCDs, 128 consecutive ids per XCD
  const int bid = blockIdx.x;
  const int wid = (bid & 7) * 128 + (bid >> 3);
  const int qt = wid & 7, bh = wid >> 3;
  const int b = bh >> 4, h = bh & 15;
  const int t = threadIdx.x, w = t >> 6, l = t & 63;
  const int ln = l & 31, hi = l >> 5;

  __shared__ AttnSMem sm;

  const int qbase = qt * 128 + w * 32;

  // ---- staging constants (pre-swizzled global source, rule 21) ----
  const int row0 = w * 8 + (l >> 3);
  const int srcoff = (((l & 7) ^ ((l >> 3) & 7)) << 3);
  const u16* kS0 = Yk + ((size_t)(b * S_N + row0) * D_N + h * HD_N + srcoff);
  const u16* vS0 = Yv + ((size_t)(b * D_N + h * HD_N + row0) * S_N + srcoff);

#define STAGE(buf, tt)                                                        \
  do {                                                                        \
    const u16* ka_ = kS0 + (size_t)(tt) * 64 * D_N;                           \
    const u16* va_ = vS0 + (tt) * 64;                                         \
    gl_lds16(ka_, sm.st.K[buf] + w * 512);                                    \
    gl_lds16(ka_ + (size_t)32 * D_N, sm.st.K[buf] + 2048 + w * 512);          \
    gl_lds16(va_, sm.st.V[buf] + w * 512);                                    \
    gl_lds16(va_ + (size_t)32 * S_N, sm.st.V[buf] + 2048 + w * 512);          \
  } while (0)

  STAGE(0, 0);

  bfrag qf[4];
  {
    const u16* qp = Yq + ((size_t)(b * S_N + qbase + ln) * D_N + h * HD_N + hi * 8);
#pragma unroll
    for (int c = 0; c < 4; ++c) qf[c] = *(const bfrag*)(qp + c * 16);
  }

  int kcol[4];
#pragma unroll
  for (int c = 0; c < 4; ++c)
    kcol[c] = (((c * 32 + hi * 16) ^ ((ln & 7) << 4)) >> 1);

  f32x16 o0, o1;
#pragma unroll
  for (int r = 0; r < 16; ++r) { o0[r] = 0.f; o1[r] = 0.f; }
  float m_r = -3.0e38f, l_r = 0.f;

  __syncthreads();  // tile 0 staged (drains vmcnt)

  int cur = 0;
  for (int kt = 0; kt < 16; ++kt) {
    if (kt < 15) STAGE(cur ^ 1, kt + 1);

    const u16* Kb = sm.st.K[cur];
    const u16* Vb = sm.st.V[cur];

    bfrag kf[8];
#pragma unroll
    for (int s2 = 0; s2 < 2; ++s2)
#pragma unroll
      for (int c = 0; c < 4; ++c)
        kf[s2 * 4 + c] = *(const bfrag*)(Kb + (s2 * 32 + ln) * 64 + kcol[c]);

    f32x16 sa, sb;
#pragma unroll
    for (int r = 0; r < 16; ++r) { sa[r] = 0.f; sb[r] = 0.f; }
    __builtin_amdgcn_s_setprio(1);
#pragma unroll
    for (int c = 0; c < 4; ++c) {
      sa = __builtin_amdgcn_mfma_f32_32x32x16_bf16(kf[c], qf[c], sa, 0, 0, 0);
      sb = __builtin_amdgcn_mfma_f32_32x32x16_bf16(kf[4 + c], qf[c], sb, 0, 0, 0);
    }
    __builtin_amdgcn_s_setprio(0);

    bfrag vf[8];
#pragma unroll
    for (int hf = 0; hf < 2; ++hf)
#pragma unroll
      for (int c = 0; c < 4; ++c)
        vf[hf * 4 + c] = *(const bfrag*)(Vb + (hf * 32 + ln) * 64 + kcol[c]);

    // ---- online softmax, in-lane, tree reductions ----
    float t16[16];
#pragma unroll
    for (int r = 0; r < 16; ++r) t16[r] = fmaxf(sa[r], sb[r]);
    float t8[8];
#pragma unroll
    for (int r = 0; r < 8; ++r) t8[r] = fmaxf(t16[r], t16[r + 8]);
    float t4[4];
#pragma unroll
    for (int r = 0; r < 4; ++r) t4[r] = fmaxf(t8[r], t8[r + 4]);
    float pmax = fmaxf(fmaxf(t4[0], t4[1]), fmaxf(t4[2], t4[3]));
    pmax = xhalf_max(pmax);

    if (__any(pmax > m_r + 8.f)) {  // defer-max (T13)
      const float mnew = fmaxf(m_r, pmax);
      const float corr = exp2f(m_r - mnew);
#pragma unroll
      for (int r = 0; r < 16; ++r) { o0[r] *= corr; o1[r] *= corr; }
      l_r *= corr;
      m_r = mnew;
    }

#pragma unroll
    for (int r = 0; r < 16; ++r) sa[r] = exp2f(sa[r] - m_r);
#pragma unroll
    for (int r = 0; r < 16; ++r) sb[r] = exp2f(sb[r] - m_r);
    float s16[16];
#pragma unroll
    for (int r = 0; r < 16; ++r) s16[r] = sa[r] + sb[r];
    float s8[8];
#pragma unroll
    for (int r = 0; r < 8; ++r) s8[r] = s16[r] + s16[r + 8];
    float s4[4];
#pragma unroll
    for (int r = 0; r < 4; ++r) s4[r] = s8[r] + s8[r + 4];
    float rsum = (s4[0] + s4[1]) + (s4[2] + s4[3]);
    l_r += xhalf_add(rsum);

    // ---- pack P to bf16 (cvt_pk + permlane32_swap) + PV ----
    __builtin_amdgcn_s_setprio(1);
#pragma unroll
    for (int c = 0; c < 4; ++c) {
      const int bs = (c & 1) * 8;
      float p0, p1, p2, p3, p4, p5, p6, p7;
      if (c < 2) {
        p0 = sa[bs + 0]; p1 = sa[bs + 1]; p2 = sa[bs + 2]; p3 = sa[bs + 3];
        p4 = sa[bs + 4]; p5 = sa[bs + 5]; p6 = sa[bs + 6]; p7 = sa[bs + 7];
      } else {
        p0 = sb[bs + 0]; p1 = sb[bs + 1]; p2 = sb[bs + 2]; p3 = sb[bs + 3];
        p4 = sb[bs + 4]; p5 = sb[bs + 5]; p6 = sb[bs + 6]; p7 = sb[bs + 7];
      }
      const u32 x1 = cvtpk(p0, p1), x2 = cvtpk(p2, p3);
      const u32 y1 = cvtpk(p4, p5), y2 = cvtpk(p6, p7);
      const u32x2 s1 = pl32swap(x1, y1);
      const u32x2 s2 = pl32swap(x2, y2);
      union { u32 u[4]; bfrag v; } pu;
      pu.u[0] = s1[0]; pu.u[1] = s2[0]; pu.u[2] = s1[1]; pu.u[3] = s2[1];
      o0 = __builtin_amdgcn_mfma_f32_32x32x16_bf16(vf[c], pu.v, o0, 0, 0, 0);
      o1 = __builtin_amdgcn_mfma_f32_32x32x16_bf16(vf[4 + c], pu.v, o1, 0, 0, 0);
    }
    __builtin_amdgcn_s_setprio(0);

    __syncthreads();  // drains vmcnt(0): next tile staged; frees buf[cur]
    cur ^= 1;
  }

  // ---- epilogue: normalize, transpose O^T -> O via LDS (2 half-passes) ----
  const float inv = 1.f / l_r;
  float* ow = sm.ol[w];
  const int qr = l >> 1, ch = l & 1;
  const float* rp = ow + qr * 34 + ch * 16;
  float* op = out + ((size_t)(b * S_N + qbase + qr) * D_N + h * HD_N + ch * 16);

#pragma unroll
  for (int g = 0; g < 4; ++g) {
    f32x4 v;
#pragma unroll
    for (int j = 0; j < 4; ++j) v[j] = o0[g * 4 + j] * inv;
    *(f32x4*)(ow + ln * 34 + g * 8 + hi * 4) = v;
  }
  asm volatile("s_waitcnt lgkmcnt(0)" ::: "memory");
  __builtin_amdgcn_sched_barrier(0);
#pragma unroll
  for (int j = 0; j < 4; ++j)
    *(f32x4*)(op + j * 4) = *(const f32x4*)(rp + j * 4);
  asm volatile("s_waitcnt lgkmcnt(0)" ::: "memory");
  __builtin_amdgcn_sched_barrier(0);

#pragma unroll
  for (int g = 0; g < 4; ++g) {
    f32x4 v;
#pragma unroll
    for (int j = 0; j < 4; ++j) v[j] = o1[g * 4 + j] * inv;
    *(f32x4*)(ow + ln * 34 + g * 8 + hi * 4) = v;
  }
  asm volatile("s_waitcnt lgkmcnt(0)" ::: "memory");
  __builtin_amdgcn_sched_barrier(0);
#pragma unroll
  for (int j = 0; j < 4; ++j)
    *(f32x4*)(op + 32 + j * 4) = *(const f32x4*)(rp + j * 4);
#undef STAGE
}

// ---------------------------------------------------------------------------
extern "C" void kernel_launch(void* const* d_in, const int* in_sizes, int n_in,
                              void* d_out, int out_size, void* d_ws, size_t ws_size,
                              hipStream_t stream) {
  const float* Qs = (const float*)d_in[0];
  const float* Ks = (const float*)d_in[1];
  const float* Vs = (const float*)d_in[2];
  const float* WQ = (const float*)d_in[3];
  const float* WK = (const float*)d_in[4];
  const float* WV = (const float*)d_in[5];
  if (ws_size < 106954752ull) return;  // need ~102 MiB scratch

  u16* Xbf = (u16*)d_ws;             // 3 * 8,388,608
  u16* Wbf = Xbf + 25165824;         // 3 * 1,048,576
  u16* Ybf = Wbf + 3145728;          // 3 * 8,388,608
  float* out = (float*)d_out;

  cvt3<<<dim3(8192, 3), 256, 0, stream>>>(Qs, Ks, Vs, Xbf, Xbf + 8388608,
                                          Xbf + 16777216, 2097152);
  cvt3<<<dim3(1024, 3), 256, 0, stream>>>(WQ, WK, WV, Wbf, Wbf + 1048576,
                                          Wbf + 2097152, 262144);
  gemm_qkv<<<dim3(384), 512, 0, stream>>>(Xbf, Wbf, Ybf);
  attn_fwd<<<dim3(1024), 256, 0, stream>>>(Ybf, Ybf + 8388608, Ybf + 16777216, out);
}

// Round 6
// 167.557 us; speedup vs baseline: 1.6754x; 1.0742x over previous
//
#include <hip/hip_runtime.h>
#include <stdint.h>

// ---------------------------------------------------------------------------
// SelfAttention: B=8,S=1024,D=1024,H=16,HD=64
//   Y{q,k,v} = X @ W^T (bf16 MFMA, fp32 acc), then flash attention.
//   Q epilogue folds scale 0.125 * log2(e) so softmax uses exp2f.
//   V is written transposed [B][D][S] so PV A-fragments read V^T rows.
// Round 6: attn K/V staging goes triple-buffered with counted vmcnt(4) and
//   raw s_barrier (T4): the per-tile __syncthreads vmcnt(0) drain was ~65us
//   of stall. Loads now have 2 tiles of compute to land; the end-of-tile
//   wait covers only loads issued a full tile earlier.
//   vmcnt ledger (per wave): Q loads issued first (oldest, drained by
//   compiler before tile-0 MFMA). Steady state in flight at wait point =
//   {kt+1:4, kt+2:4} -> vmcnt(4) retires kt+1. kt=14: no new stage ->
//   vmcnt(0) retires t15. Buffer (kt+2)%3 is freed by the barrier at the
//   end of kt-1 (all waves' reads of kt-1 complete before it).
// ws layout (bytes):
//   [0)            Xbf : 3 * 8192*1024 bf16   (50,331,648)
//   [50331648)     Wbf : 3 * 1024*1024 bf16   ( 6,291,456)
//   [56623104)     Ybf : 3 * 8192*1024 bf16   (50,331,648)  total 106,954,752
// ---------------------------------------------------------------------------

#define B_N 8
#define S_N 1024
#define D_N 1024
#define H_N 16
#define HD_N 64
#define M_N (B_N * S_N) /* 8192 */

typedef __bf16 bfrag __attribute__((ext_vector_type(8)));
typedef float f32x4 __attribute__((ext_vector_type(4)));
typedef float f32x16 __attribute__((ext_vector_type(16)));
typedef unsigned int u32;
typedef u32 u32x2 __attribute__((ext_vector_type(2)));
typedef unsigned short u16;

__device__ __forceinline__ u16 f2bf(float f) {  // RNE fp32 -> bf16 bits
  uint32_t u = __float_as_uint(f);
  u += 0x7FFFu + ((u >> 16) & 1u);
  return (u16)(u >> 16);
}

__device__ __forceinline__ void gl_lds16(const void* g, void* l) {
  __builtin_amdgcn_global_load_lds(
      (const __attribute__((address_space(1))) uint32_t*)g,
      (__attribute__((address_space(3))) uint32_t*)l, 16, 0, 0);
}

__device__ __forceinline__ u32 cvtpk(float lo, float hi) {
  u32 r;
  asm("v_cvt_pk_bf16_f32 %0, %1, %2" : "=v"(r) : "v"(lo), "v"(hi));
  return r;
}

__device__ __forceinline__ u32x2 pl32swap(u32 a, u32 b) {
#if __has_builtin(__builtin_amdgcn_permlane32_swap)
  return __builtin_amdgcn_permlane32_swap(a, b, false, false);
#else
  u32 sa = (u32)__shfl_xor((int)a, 32, 64), sb = (u32)__shfl_xor((int)b, 32, 64);
  const bool hi = (threadIdx.x & 32) != 0;
  u32x2 r;
  r[0] = hi ? sb : a;
  r[1] = hi ? b : sa;
  return r;
#endif
}

__device__ __forceinline__ float xhalf_max(float v) {
  u32x2 r = pl32swap(__float_as_uint(v), __float_as_uint(v));
  return fmaxf(__uint_as_float(r[0]), __uint_as_float(r[1]));
}
__device__ __forceinline__ float xhalf_add(float v) {
  u32x2 r = pl32swap(__float_as_uint(v), __float_as_uint(v));
  return __uint_as_float(r[0]) + __uint_as_float(r[1]);
}

// ---------------- fp32 -> bf16 conversion (3 arrays per launch) ------------
__global__ void cvt3(const float* __restrict__ s0, const float* __restrict__ s1,
                     const float* __restrict__ s2, u16* __restrict__ d0,
                     u16* __restrict__ d1, u16* __restrict__ d2, int n4) {
  const float* s = blockIdx.y == 0 ? s0 : (blockIdx.y == 1 ? s1 : s2);
  u16* d = blockIdx.y == 0 ? d0 : (blockIdx.y == 1 ? d1 : d2);
  int i = blockIdx.x * 256 + threadIdx.x;
  if (i < n4) {
    float4 v = ((const float4*)s)[i];
    ushort4 o;
    o.x = f2bf(v.x); o.y = f2bf(v.y); o.z = f2bf(v.z); o.w = f2bf(v.w);
    ((ushort4*)d)[i] = o;
  }
}

// ---------------- projection GEMM: 256^2 8-phase (m201-style) --------------
__global__ __launch_bounds__(512, 2) void gemm_qkv(const u16* __restrict__ Xbf,
                                                   const u16* __restrict__ Wbf,
                                                   u16* __restrict__ Ybf) {
  const int bid = blockIdx.x;
  const int wid = (bid & 7) * 48 + (bid >> 3);  // bijective: 384 % 8 == 0
  const int mat = wid >> 7;
  const int rem = wid & 127;
  const int m0 = (rem >> 2) * 256;
  const int n0 = (rem & 3) * 256;

  const u16* A = Xbf + (size_t)mat * (M_N * D_N);
  const u16* Bw = Wbf + (size_t)mat * (D_N * D_N);
  u16* Y = Ybf + (size_t)mat * (M_N * D_N);

  __shared__ u16 Ast[2][4][4096];  // [dbuf][qm*2+ha][64x64], 64 KB
  __shared__ u16 Bst[2][4][4096];  // [dbuf][qn*2+hb][64x64], 64 KB

  const int t = threadIdx.x;
  const int w = t >> 6, l = t & 63;
  const int lr = l & 15, lg = l >> 4;
  const int wm = w >> 2, wn = w & 3;
  const int hb = wn >> 1;

  const int swcol = (((t & 7) ^ ((t >> 3) & 7)) << 3);
  const u16* aSrc = A + (size_t)(m0 + (t >> 3)) * D_N + swcol;
  const u16* bSrc =
      Bw + (size_t)(n0 + (t >> 8) * 64 + ((t >> 3) & 31)) * D_N + swcol;

  const int asw = (lr & 7) << 3;
  const int aoff0 = (lg * 8) ^ asw;
  const int aoff1 = (32 + lg * 8) ^ asw;
  const int brow = ((wn & 1) * 32 + lr) * 64;

#define STA(d, qm_, ha_, tt)                                                  \
  gl_lds16(aSrc + (size_t)((ha_)*128 + (qm_)*64) * D_N + (tt)*64,             \
           &Ast[d][(qm_)*2 + (ha_)][w * 512])
#define STB(d, qn_, hb_, tt)                                                  \
  gl_lds16(bSrc + (size_t)((hb_)*128 + (qn_)*32) * D_N + (tt)*64,             \
           &Bst[d][(qn_)*2 + (hb_)][w * 512])
#define LDA(AR, D, QM)                                                        \
  do {                                                                        \
    const u16* p_ = &Ast[D][(QM)*2 + wm][lr * 64];                            \
    AR[0][0] = *(const bfrag*)(p_ + aoff0);                                   \
    AR[0][1] = *(const bfrag*)(p_ + aoff1);                                   \
    AR[1][0] = *(const bfrag*)(p_ + 1024 + aoff0);                            \
    AR[1][1] = *(const bfrag*)(p_ + 1024 + aoff1);                            \
    AR[2][0] = *(const bfrag*)(p_ + 2048 + aoff0);                            \
    AR[2][1] = *(const bfrag*)(p_ + 2048 + aoff1);                            \
    AR[3][0] = *(const bfrag*)(p_ + 3072 + aoff0);                            \
    AR[3][1] = *(const bfrag*)(p_ + 3072 + aoff1);                            \
  } while (0)
#define LDB(BR, D, QN)                                                        \
  do {                                                                        \
    const u16* p_ = &Bst[D][(QN)*2 + hb][brow];                               \
    BR[0][0] = *(const bfrag*)(p_ + aoff0);                                   \
    BR[0][1] = *(const bfrag*)(p_ + aoff1);                                   \
    BR[1][0] = *(const bfrag*)(p_ + 1024 + aoff0);                            \
    BR[1][1] = *(const bfrag*)(p_ + 1024 + aoff1);                            \
  } while (0)
#define MMA(QM, QN, AR, BR)                                                   \
  do {                                                                        \
    __builtin_amdgcn_s_setprio(1);                                            \
    _Pragma("unroll") for (int mf_ = 0; mf_ < 4; ++mf_)                       \
    _Pragma("unroll") for (int j_ = 0; j_ < 2; ++j_)                          \
    _Pragma("unroll") for (int kk_ = 0; kk_ < 2; ++kk_)                       \
      acc[(QM)*4 + mf_][(QN)*2 + j_] =                                        \
          __builtin_amdgcn_mfma_f32_16x16x32_bf16(                            \
              AR[mf_][kk_], BR[j_][kk_], acc[(QM)*4 + mf_][(QN)*2 + j_],      \
              0, 0, 0);                                                       \
    __builtin_amdgcn_s_setprio(0);                                            \
  } while (0)
#define BARR()                                                                \
  __builtin_amdgcn_s_barrier();                                               \
  __builtin_amdgcn_sched_barrier(0)
#define WAITL()                                                               \
  asm volatile("s_waitcnt lgkmcnt(0)" ::: "memory");                          \
  __builtin_amdgcn_sched_barrier(0)
#define WAITV4()                                                              \
  asm volatile("s_waitcnt vmcnt(4)" ::: "memory");                            \
  __builtin_amdgcn_sched_barrier(0)

  f32x4 acc[8][4];
#pragma unroll
  for (int i = 0; i < 8; ++i)
#pragma unroll
    for (int j = 0; j < 4; ++j) acc[i][j] = (f32x4){0.f, 0.f, 0.f, 0.f};

  // prologue: tile0 full -> dbuf0; tile1 {A0, B1} -> dbuf1 (A1,B0 at P1)
  STA(0, 0, 0, 0); STA(0, 0, 1, 0); STA(0, 1, 0, 0); STA(0, 1, 1, 0);
  STB(0, 0, 0, 0); STB(0, 0, 1, 0); STB(0, 1, 0, 0); STB(0, 1, 1, 0);
  STA(1, 0, 0, 1); STA(1, 0, 1, 1); STB(1, 1, 0, 1); STB(1, 1, 1, 1);
  WAITV4();  // tile0's 8 landed; tile1's 4 still in flight
  BARR();

  bfrag a[4][2], a2[4][2], b0[2][2], b1[2][2];

  for (int it = 0; it < 8; ++it) {
    const int T1 = 2 * it + 1, TN = 2 * it + 2;
    const bool st = (it < 7);
    // ---- P1: q(0,0) on dbuf0; stage T1's A1,B0 -> dbuf1
    LDA(a, 0, 0);
    LDB(b0, 0, 0);
    STA(1, 1, 0, T1); STA(1, 1, 1, T1); STB(1, 0, 0, T1); STB(1, 0, 1, T1);
    BARR(); WAITL();
    MMA(0, 0, a, b0);
    BARR();
    // ---- P2: q(0,1)
    LDB(b1, 0, 1);
    BARR(); WAITL();
    MMA(0, 1, a, b1);
    BARR();
    // ---- P3: q(1,1); stage TN's A0 -> dbuf0
    LDA(a2, 0, 1);
    if (st) { STA(0, 0, 0, TN); STA(0, 0, 1, TN); }
    BARR(); WAITL();
    MMA(1, 1, a2, b1);
    BARR();
    // ---- P4: q(1,0); stage TN's B1 -> dbuf0; counted vmcnt
    if (st) { STB(0, 1, 0, TN); STB(0, 1, 1, TN); }
    BARR();
    MMA(1, 0, a2, b0);
    WAITV4();
    BARR();
    // ---- P5: q(0,0) on dbuf1; stage TN's A1,B0 -> dbuf0
    LDA(a, 1, 0);
    LDB(b0, 1, 0);
    if (st) { STA(0, 1, 0, TN); STA(0, 1, 1, TN); STB(0, 0, 0, TN); STB(0, 0, 1, TN); }
    BARR(); WAITL();
    MMA(0, 0, a, b0);
    BARR();
    // ---- P6: q(0,1)
    LDB(b1, 1, 1);
    BARR(); WAITL();
    MMA(0, 1, a, b1);
    BARR();
    // ---- P7: q(1,1); stage (TN+1)'s A0 -> dbuf1
    LDA(a2, 1, 1);
    if (st) { STA(1, 0, 0, TN + 1); STA(1, 0, 1, TN + 1); }
    BARR(); WAITL();
    MMA(1, 1, a2, b1);
    BARR();
    // ---- P8: q(1,0); stage (TN+1)'s B1 -> dbuf1; counted vmcnt
    if (st) { STB(1, 1, 0, TN + 1); STB(1, 1, 1, TN + 1); }
    BARR();
    MMA(1, 0, a2, b0);
    WAITV4();
    BARR();
  }

  // ---- epilogue ----
  const float alpha = (mat == 0) ? 0.18033688011112042f : 1.0f;
  const int mrow = m0 + wm * 128;
  const int ncol = n0 + (wn >> 1) * 128 + (wn & 1) * 64;
  if (mat < 2) {
#pragma unroll
    for (int qm = 0; qm < 2; ++qm)
#pragma unroll
      for (int mf = 0; mf < 4; ++mf)
#pragma unroll
        for (int qn = 0; qn < 2; ++qn)
#pragma unroll
          for (int j = 0; j < 2; ++j) {
            const int row0 = mrow + qm * 64 + mf * 16 + lg * 4;
            const int col = ncol + qn * 32 + j * 16 + lr;
#pragma unroll
            for (int r = 0; r < 4; ++r)
              Y[(size_t)(row0 + r) * D_N + col] =
                  f2bf(acc[qm * 4 + mf][qn * 2 + j][r] * alpha);
          }
  } else {
    const int b = m0 >> 10;
    const int sbase = (m0 & 1023) + wm * 128;
#pragma unroll
    for (int qm = 0; qm < 2; ++qm)
#pragma unroll
      for (int mf = 0; mf < 4; ++mf)
#pragma unroll
        for (int qn = 0; qn < 2; ++qn)
#pragma unroll
          for (int j = 0; j < 2; ++j) {
            const int s0 = sbase + qm * 64 + mf * 16 + lg * 4;
            const int col = ncol + qn * 32 + j * 16 + lr;
            const f32x4 v = acc[qm * 4 + mf][qn * 2 + j];
            ushort4 pk;
            pk.x = f2bf(v[0]); pk.y = f2bf(v[1]);
            pk.z = f2bf(v[2]); pk.w = f2bf(v[3]);
            *(ushort4*)(Y + (size_t)(b * D_N + col) * S_N + s0) = pk;
          }
  }
#undef STA
#undef STB
#undef LDA
#undef LDB
#undef MMA
#undef BARR
#undef WAITL
#undef WAITV4
}

// ---------------- flash attention (tri-buffered LDS K/V, counted vmcnt) ----
union AttnSMem {
  struct { u16 K[3][4096]; u16 V[3][4096]; } st;  // 48 KB, triple-buffered
  float ol[4][32 * 34];                           // epilogue transpose (17 KB)
};

__global__ __launch_bounds__(256, 3) void attn_fwd(const u16* __restrict__ Yq,
                                                   const u16* __restrict__ Yk,
                                                   const u16* __restrict__ Yv,
                                                   float* __restrict__ out) {
  // XCD-chunked work id: 1024 blocks, 8 XCDs, 128 consecutive ids per XCD
  const int bid = blockIdx.x;
  const int wid = (bid & 7) * 128 + (bid >> 3);
  const int qt = wid & 7, bh = wid >> 3;
  const int b = bh >> 4, h = bh & 15;
  const int t = threadIdx.x, w = t >> 6, l = t & 63;
  const int ln = l & 31, hi = l >> 5;

  __shared__ AttnSMem sm;

  const int qbase = qt * 128 + w * 32;

  // ---- staging constants (pre-swizzled global source, rule 21) ----
  const int row0 = w * 8 + (l >> 3);
  const int srcoff = (((l & 7) ^ ((l >> 3) & 7)) << 3);
  const u16* kS0 = Yk + ((size_t)(b * S_N + row0) * D_N + h * HD_N + srcoff);
  const u16* vS0 = Yv + ((size_t)(b * D_N + h * HD_N + row0) * S_N + srcoff);

#define STAGE(buf, tt)                                                        \
  do {                                                                        \
    const u16* ka_ = kS0 + (size_t)(tt) * 64 * D_N;                           \
    const u16* va_ = vS0 + (tt) * 64;                                         \
    gl_lds16(ka_, sm.st.K[buf] + w * 512);                                    \
    gl_lds16(ka_ + (size_t)32 * D_N, sm.st.K[buf] + 2048 + w * 512);          \
    gl_lds16(va_, sm.st.V[buf] + w * 512);                                    \
    gl_lds16(va_ + (size_t)32 * S_N, sm.st.V[buf] + 2048 + w * 512);          \
  } while (0)

  // Q loads FIRST (oldest in the vm queue; compiler drains them before
  // tile-0's MFMA without touching the stage-load counting below).
  bfrag qf[4];
  {
    const u16* qp = Yq + ((size_t)(b * S_N + qbase + ln) * D_N + h * HD_N + hi * 8);
#pragma unroll
    for (int c = 0; c < 4; ++c) qf[c] = *(const bfrag*)(qp + c * 16);
  }

  // prologue: stage tiles 0 and 1
  STAGE(0, 0);
  STAGE(1, 1);

  int kcol[4];
#pragma unroll
  for (int c = 0; c < 4; ++c)
    kcol[c] = (((c * 32 + hi * 16) ^ ((ln & 7) << 4)) >> 1);

  f32x16 o0, o1;
#pragma unroll
  for (int r = 0; r < 16; ++r) { o0[r] = 0.f; o1[r] = 0.f; }
  float m_r = -3.0e38f, l_r = 0.f;

  // wait tile 0 (qf:4 + t0:4 retired, t1:4 may fly), then publish
  asm volatile("s_waitcnt vmcnt(4)" ::: "memory");
  __builtin_amdgcn_sched_barrier(0);
  __builtin_amdgcn_s_barrier();

  int rd = 0, sb = 2;  // read buffer kt%3; stage buffer (kt+2)%3
  for (int kt = 0; kt < 16; ++kt) {
    if (kt < 14) STAGE(sb, kt + 2);

    const u16* Kb = sm.st.K[rd];
    const u16* Vb = sm.st.V[rd];

    bfrag kf[8];
#pragma unroll
    for (int s2 = 0; s2 < 2; ++s2)
#pragma unroll
      for (int c = 0; c < 4; ++c)
        kf[s2 * 4 + c] = *(const bfrag*)(Kb + (s2 * 32 + ln) * 64 + kcol[c]);

    f32x16 sa, sbv;
#pragma unroll
    for (int r = 0; r < 16; ++r) { sa[r] = 0.f; sbv[r] = 0.f; }
    __builtin_amdgcn_s_setprio(1);
#pragma unroll
    for (int c = 0; c < 4; ++c) {
      sa = __builtin_amdgcn_mfma_f32_32x32x16_bf16(kf[c], qf[c], sa, 0, 0, 0);
      sbv = __builtin_amdgcn_mfma_f32_32x32x16_bf16(kf[4 + c], qf[c], sbv, 0, 0, 0);
    }
    __builtin_amdgcn_s_setprio(0);

    bfrag vf[8];
#pragma unroll
    for (int hf = 0; hf < 2; ++hf)
#pragma unroll
      for (int c = 0; c < 4; ++c)
        vf[hf * 4 + c] = *(const bfrag*)(Vb + (hf * 32 + ln) * 64 + kcol[c]);

    // ---- online softmax, in-lane, tree reductions ----
    float t16[16];
#pragma unroll
    for (int r = 0; r < 16; ++r) t16[r] = fmaxf(sa[r], sbv[r]);
    float t8[8];
#pragma unroll
    for (int r = 0; r < 8; ++r) t8[r] = fmaxf(t16[r], t16[r + 8]);
    float t4[4];
#pragma unroll
    for (int r = 0; r < 4; ++r) t4[r] = fmaxf(t8[r], t8[r + 4]);
    float pmax = fmaxf(fmaxf(t4[0], t4[1]), fmaxf(t4[2], t4[3]));
    pmax = xhalf_max(pmax);

    if (__any(pmax > m_r + 8.f)) {  // defer-max (T13)
      const float mnew = fmaxf(m_r, pmax);
      const float corr = exp2f(m_r - mnew);
#pragma unroll
      for (int r = 0; r < 16; ++r) { o0[r] *= corr; o1[r] *= corr; }
      l_r *= corr;
      m_r = mnew;
    }

#pragma unroll
    for (int r = 0; r < 16; ++r) sa[r] = exp2f(sa[r] - m_r);
#pragma unroll
    for (int r = 0; r < 16; ++r) sbv[r] = exp2f(sbv[r] - m_r);
    float s16[16];
#pragma unroll
    for (int r = 0; r < 16; ++r) s16[r] = sa[r] + sbv[r];
    float s8[8];
#pragma unroll
    for (int r = 0; r < 8; ++r) s8[r] = s16[r] + s16[r + 8];
    float s4[4];
#pragma unroll
    for (int r = 0; r < 4; ++r) s4[r] = s8[r] + s8[r + 4];
    float rsum = (s4[0] + s4[1]) + (s4[2] + s4[3]);
    l_r += xhalf_add(rsum);

    // ---- pack P to bf16 (cvt_pk + permlane32_swap) + PV ----
    __builtin_amdgcn_s_setprio(1);
#pragma unroll
    for (int c = 0; c < 4; ++c) {
      const int bs = (c & 1) * 8;
      float p0, p1, p2, p3, p4, p5, p6, p7;
      if (c < 2) {
        p0 = sa[bs + 0]; p1 = sa[bs + 1]; p2 = sa[bs + 2]; p3 = sa[bs + 3];
        p4 = sa[bs + 4]; p5 = sa[bs + 5]; p6 = sa[bs + 6]; p7 = sa[bs + 7];
      } else {
        p0 = sbv[bs + 0]; p1 = sbv[bs + 1]; p2 = sbv[bs + 2]; p3 = sbv[bs + 3];
        p4 = sbv[bs + 4]; p5 = sbv[bs + 5]; p6 = sbv[bs + 6]; p7 = sbv[bs + 7];
      }
      const u32 x1 = cvtpk(p0, p1), x2 = cvtpk(p2, p3);
      const u32 y1 = cvtpk(p4, p5), y2 = cvtpk(p6, p7);
      const u32x2 s1 = pl32swap(x1, y1);
      const u32x2 s2 = pl32swap(x2, y2);
      union { u32 u[4]; bfrag v; } pu;
      pu.u[0] = s1[0]; pu.u[1] = s2[0]; pu.u[2] = s1[1]; pu.u[3] = s2[1];
      o0 = __builtin_amdgcn_mfma_f32_32x32x16_bf16(vf[c], pu.v, o0, 0, 0, 0);
      o1 = __builtin_amdgcn_mfma_f32_32x32x16_bf16(vf[4 + c], pu.v, o1, 0, 0, 0);
    }
    __builtin_amdgcn_s_setprio(0);

    // counted wait: retire tile kt+1's stages (issued a full tile ago);
    // tail (kt>=14): drain remaining. Then publish via raw barrier.
    if (kt < 14) {
      asm volatile("s_waitcnt vmcnt(4)" ::: "memory");
    } else {
      asm volatile("s_waitcnt vmcnt(0)" ::: "memory");
    }
    __builtin_amdgcn_sched_barrier(0);
    __builtin_amdgcn_s_barrier();

    rd = (rd == 2) ? 0 : rd + 1;
    sb = (sb == 2) ? 0 : sb + 1;
  }

  // ---- epilogue: normalize, transpose O^T -> O via LDS (2 half-passes) ----
  const float inv = 1.f / l_r;
  float* ow = sm.ol[w];
  const int qr = l >> 1, ch = l & 1;
  const float* rp = ow + qr * 34 + ch * 16;
  float* op = out + ((size_t)(b * S_N + qbase + qr) * D_N + h * HD_N + ch * 16);

#pragma unroll
  for (int g = 0; g < 4; ++g) {
    f32x4 v;
#pragma unroll
    for (int j = 0; j < 4; ++j) v[j] = o0[g * 4 + j] * inv;
    *(f32x4*)(ow + ln * 34 + g * 8 + hi * 4) = v;
  }
  asm volatile("s_waitcnt lgkmcnt(0)" ::: "memory");
  __builtin_amdgcn_sched_barrier(0);
#pragma unroll
  for (int j = 0; j < 4; ++j)
    *(f32x4*)(op + j * 4) = *(const f32x4*)(rp + j * 4);
  asm volatile("s_waitcnt lgkmcnt(0)" ::: "memory");
  __builtin_amdgcn_sched_barrier(0);

#pragma unroll
  for (int g = 0; g < 4; ++g) {
    f32x4 v;
#pragma unroll
    for (int j = 0; j < 4; ++j) v[j] = o1[g * 4 + j] * inv;
    *(f32x4*)(ow + ln * 34 + g * 8 + hi * 4) = v;
  }
  asm volatile("s_waitcnt lgkmcnt(0)" ::: "memory");
  __builtin_amdgcn_sched_barrier(0);
#pragma unroll
  for (int j = 0; j < 4; ++j)
    *(f32x4*)(op + 32 + j * 4) = *(const f32x4*)(rp + j * 4);
#undef STAGE
}

// ---------------------------------------------------------------------------
extern "C" void kernel_launch(void* const* d_in, const int* in_sizes, int n_in,
                              void* d_out, int out_size, void* d_ws, size_t ws_size,
                              hipStream_t stream) {
  const float* Qs = (const float*)d_in[0];
  const float* Ks = (const float*)d_in[1];
  const float* Vs = (const float*)d_in[2];
  const float* WQ = (const float*)d_in[3];
  const float* WK = (const float*)d_in[4];
  const float* WV = (const float*)d_in[5];
  if (ws_size < 106954752ull) return;  // need ~102 MiB scratch

  u16* Xbf = (u16*)d_ws;             // 3 * 8,388,608
  u16* Wbf = Xbf + 25165824;         // 3 * 1,048,576
  u16* Ybf = Wbf + 3145728;          // 3 * 8,388,608
  float* out = (float*)d_out;

  cvt3<<<dim3(8192, 3), 256, 0, stream>>>(Qs, Ks, Vs, Xbf, Xbf + 8388608,
                                          Xbf + 16777216, 2097152);
  cvt3<<<dim3(1024, 3), 256, 0, stream>>>(WQ, WK, WV, Wbf, Wbf + 1048576,
                                          Wbf + 2097152, 262144);
  gemm_qkv<<<dim3(384), 512, 0, stream>>>(Xbf, Wbf, Ybf);
  attn_fwd<<<dim3(1024), 256, 0, stream>>>(Ybf, Ybf + 8388608, Ybf + 16777216, out);
}

// Round 7
// 159.937 us; speedup vs baseline: 1.7552x; 1.0476x over previous
//
#include <hip/hip_runtime.h>
#include <stdint.h>

// ---------------------------------------------------------------------------
// SelfAttention: B=8,S=1024,D=1024,H=16,HD=64
//   Y{q,k,v} = X @ W^T (bf16 MFMA, fp32 acc), then flash attention.
//   Q epilogue folds scale 0.125 * log2(e) so softmax uses exp2f.
//   V is written transposed [B][D][S] so PV A-fragments read V^T rows.
// Round 7: gemm tile 256x128 -> 768 blocks = EXACTLY 3 dispatch rounds of
//   256 CUs (was 384 = 1.5 rounds, half machine idle in round 2).
//   Triple-buffered LDS (144 KB), counted vmcnt(6) ledger as in attn:
//   stage t+2 during t; end-of-tile vmcnt(6) retires t+1; vmcnt(0) only at
//   tail. 8 waves 4Mx2N (64x64/wave), 2 phases/K-tile of 16 MFMA.
// ws layout (bytes):
//   [0)            Xbf : 3 * 8192*1024 bf16   (50,331,648)
//   [50331648)     Wbf : 3 * 1024*1024 bf16   ( 6,291,456)
//   [56623104)     Ybf : 3 * 8192*1024 bf16   (50,331,648)  total 106,954,752
// ---------------------------------------------------------------------------

#define B_N 8
#define S_N 1024
#define D_N 1024
#define H_N 16
#define HD_N 64
#define M_N (B_N * S_N) /* 8192 */

typedef __bf16 bfrag __attribute__((ext_vector_type(8)));
typedef float f32x4 __attribute__((ext_vector_type(4)));
typedef float f32x16 __attribute__((ext_vector_type(16)));
typedef unsigned int u32;
typedef u32 u32x2 __attribute__((ext_vector_type(2)));
typedef unsigned short u16;

__device__ __forceinline__ u16 f2bf(float f) {  // RNE fp32 -> bf16 bits
  uint32_t u = __float_as_uint(f);
  u += 0x7FFFu + ((u >> 16) & 1u);
  return (u16)(u >> 16);
}

__device__ __forceinline__ void gl_lds16(const void* g, void* l) {
  __builtin_amdgcn_global_load_lds(
      (const __attribute__((address_space(1))) uint32_t*)g,
      (__attribute__((address_space(3))) uint32_t*)l, 16, 0, 0);
}

__device__ __forceinline__ u32 cvtpk(float lo, float hi) {
  u32 r;
  asm("v_cvt_pk_bf16_f32 %0, %1, %2" : "=v"(r) : "v"(lo), "v"(hi));
  return r;
}

__device__ __forceinline__ u32x2 pl32swap(u32 a, u32 b) {
#if __has_builtin(__builtin_amdgcn_permlane32_swap)
  return __builtin_amdgcn_permlane32_swap(a, b, false, false);
#else
  u32 sa = (u32)__shfl_xor((int)a, 32, 64), sb = (u32)__shfl_xor((int)b, 32, 64);
  const bool hi = (threadIdx.x & 32) != 0;
  u32x2 r;
  r[0] = hi ? sb : a;
  r[1] = hi ? b : sa;
  return r;
#endif
}

__device__ __forceinline__ float xhalf_max(float v) {
  u32x2 r = pl32swap(__float_as_uint(v), __float_as_uint(v));
  return fmaxf(__uint_as_float(r[0]), __uint_as_float(r[1]));
}
__device__ __forceinline__ float xhalf_add(float v) {
  u32x2 r = pl32swap(__float_as_uint(v), __float_as_uint(v));
  return __uint_as_float(r[0]) + __uint_as_float(r[1]);
}

// ---------------- fp32 -> bf16 conversion (3 arrays per launch) ------------
__global__ void cvt3(const float* __restrict__ s0, const float* __restrict__ s1,
                     const float* __restrict__ s2, u16* __restrict__ d0,
                     u16* __restrict__ d1, u16* __restrict__ d2, int n4) {
  const float* s = blockIdx.y == 0 ? s0 : (blockIdx.y == 1 ? s1 : s2);
  u16* d = blockIdx.y == 0 ? d0 : (blockIdx.y == 1 ? d1 : d2);
  int i = blockIdx.x * 256 + threadIdx.x;
  if (i < n4) {
    float4 v = ((const float4*)s)[i];
    ushort4 o;
    o.x = f2bf(v.x); o.y = f2bf(v.y); o.z = f2bf(v.z); o.w = f2bf(v.w);
    ((ushort4*)d)[i] = o;
  }
}

// ---------------- projection GEMM: 256x128 tiles, tri-buffer, counted vmcnt
// 768 blocks = 3 exact rounds. 8 waves 4Mx2N, per-wave 64x64 out.
// Ledger (per wave, 6 gl_lds per tile): stage(t+2) issued during t; at end
// of t in-flight = {t+1:6, t+2:6} -> vmcnt(6) retires t+1 (read next tile).
// kt=14 stages nothing -> vmcnt(0) drains t15. Buffer (kt+2)%3 was read in
// kt-1; all reads lgkm-complete before kt-1's final barrier -> safe.
__global__ __launch_bounds__(512, 1) void gemm_qkv(const u16* __restrict__ Xbf,
                                                   const u16* __restrict__ Wbf,
                                                   u16* __restrict__ Ybf) {
  const int bid = blockIdx.x;
  const int wid = (bid & 7) * 96 + (bid >> 3);  // bijective: 768 % 8 == 0
  const int mat = wid >> 8;                     // 256 tiles per matrix
  const int rem = wid & 255;
  const int m0 = (rem >> 3) * 256;
  const int n0 = (rem & 7) * 128;

  const u16* A = Xbf + (size_t)mat * (M_N * D_N);
  const u16* Bw = Wbf + (size_t)mat * (D_N * D_N);
  u16* Y = Ybf + (size_t)mat * (M_N * D_N);

  __shared__ u16 Ast[3][4][4096];  // [buf][chunk: 64 rows][64x64], 96 KB
  __shared__ u16 Bst[3][2][4096];  // [buf][chunk: 64 cols][64x64], 48 KB

  const int t = threadIdx.x;
  const int w = t >> 6, l = t & 63;
  const int lr = l & 15, lg = l >> 4;
  const int wm = w >> 1, wn = w & 1;

  // staging: dest linear tid*16B (row t>>3, slot t&7); source col
  // pre-swizzled so swizzled ds_read sees linear data (rule 21).
  const int swcol = (((t & 7) ^ ((t >> 3) & 7)) << 3);
  const u16* aSrc = A + (size_t)(m0 + (t >> 3)) * D_N + swcol;
  const u16* bSrc = Bw + (size_t)(n0 + (t >> 3)) * D_N + swcol;

  // swizzled ds_read column offsets (u16 units); row&7 == lr&7 for all frags
  const int asw = (lr & 7) << 3;
  const int koff0 = (lg * 8) ^ asw;
  const int koff1 = (32 + lg * 8) ^ asw;

#define STA(buf, c, tt)                                                       \
  gl_lds16(aSrc + (size_t)((c)*64) * D_N + (tt)*64, &Ast[buf][c][t * 8])
#define STB(buf, c, tt)                                                       \
  gl_lds16(bSrc + (size_t)((c)*64) * D_N + (tt)*64, &Bst[buf][c][t * 8])
#define LDA8(AR, buf)                                                         \
  do {                                                                        \
    const u16* p_ = &Ast[buf][wm][lr * 64];                                   \
    _Pragma("unroll") for (int mf_ = 0; mf_ < 4; ++mf_) {                     \
      AR[mf_][0] = *(const bfrag*)(p_ + mf_ * 1024 + koff0);                  \
      AR[mf_][1] = *(const bfrag*)(p_ + mf_ * 1024 + koff1);                  \
    }                                                                         \
  } while (0)
#define LDB4(BR, buf, h)                                                      \
  do {                                                                        \
    const u16* p_ = &Bst[buf][wn][((h)*32 + lr) * 64];                        \
    BR[0][0] = *(const bfrag*)(p_ + koff0);                                   \
    BR[0][1] = *(const bfrag*)(p_ + koff1);                                   \
    BR[1][0] = *(const bfrag*)(p_ + 1024 + koff0);                            \
    BR[1][1] = *(const bfrag*)(p_ + 1024 + koff1);                            \
  } while (0)
#define MMAH(h, AR, BR)                                                       \
  do {                                                                        \
    __builtin_amdgcn_s_setprio(1);                                            \
    _Pragma("unroll") for (int mf_ = 0; mf_ < 4; ++mf_)                       \
    _Pragma("unroll") for (int j_ = 0; j_ < 2; ++j_)                          \
    _Pragma("unroll") for (int kk_ = 0; kk_ < 2; ++kk_)                       \
      acc[mf_][(h)*2 + j_] = __builtin_amdgcn_mfma_f32_16x16x32_bf16(         \
          AR[mf_][kk_], BR[j_][kk_], acc[mf_][(h)*2 + j_], 0, 0, 0);          \
    __builtin_amdgcn_s_setprio(0);                                            \
  } while (0)
#define BARR()                                                                \
  __builtin_amdgcn_s_barrier();                                               \
  __builtin_amdgcn_sched_barrier(0)
#define WAITL()                                                               \
  asm volatile("s_waitcnt lgkmcnt(0)" ::: "memory");                          \
  __builtin_amdgcn_sched_barrier(0)
#define WAITV(n)                                                              \
  asm volatile("s_waitcnt vmcnt(" #n ")" ::: "memory");                       \
  __builtin_amdgcn_sched_barrier(0)

  f32x4 acc[4][4];
#pragma unroll
  for (int i = 0; i < 4; ++i)
#pragma unroll
    for (int j = 0; j < 4; ++j) acc[i][j] = (f32x4){0.f, 0.f, 0.f, 0.f};

  // prologue: stage tiles 0 and 1 (6 loads each)
  STA(0, 0, 0); STA(0, 1, 0); STA(0, 2, 0); STA(0, 3, 0);
  STB(0, 0, 0); STB(0, 1, 0);
  STA(1, 0, 1); STA(1, 1, 1); STA(1, 2, 1); STA(1, 3, 1);
  STB(1, 0, 1); STB(1, 1, 1);
  WAITV(6);  // tile 0 landed; tile 1 in flight
  BARR();

  int rd = 0, sg = 2;
  for (int kt = 0; kt < 16; ++kt) {
    const bool st = (kt < 14);
    bfrag a[4][2], b[2][2];
    // ---- P1: A(8) + B-half0(4) reads; stage 3 of tile kt+2
    LDA8(a, rd);
    LDB4(b, rd, 0);
    if (st) { STA(sg, 0, kt + 2); STA(sg, 1, kt + 2); STA(sg, 2, kt + 2); }
    BARR(); WAITL();
    MMAH(0, a, b);
    BARR();
    // ---- P2: B-half1(4) reads; stage remaining 3; counted vmcnt
    LDB4(b, rd, 1);
    if (st) { STA(sg, 3, kt + 2); STB(sg, 0, kt + 2); STB(sg, 1, kt + 2); }
    BARR(); WAITL();
    MMAH(1, a, b);
    if (kt < 14) { WAITV(6); } else if (kt == 14) { WAITV(0); }
    BARR();
    rd = (rd == 2) ? 0 : rd + 1;
    sg = (sg == 2) ? 0 : sg + 1;
  }

  // ---- epilogue ----
  const float alpha = (mat == 0) ? 0.18033688011112042f : 1.0f;
  const int mrow = m0 + wm * 64;
  const int ncol = n0 + wn * 64;
  if (mat < 2) {
#pragma unroll
    for (int mf = 0; mf < 4; ++mf) {
      const int row0 = mrow + mf * 16 + lg * 4;
#pragma unroll
      for (int nf = 0; nf < 4; ++nf) {
        const int col = ncol + nf * 16 + lr;
#pragma unroll
        for (int r = 0; r < 4; ++r)
          Y[(size_t)(row0 + r) * D_N + col] = f2bf(acc[mf][nf][r] * alpha);
      }
    }
  } else {
    const int b = m0 >> 10;
#pragma unroll
    for (int mf = 0; mf < 4; ++mf) {
      const int s0 = (m0 & 1023) + wm * 64 + mf * 16 + lg * 4;
#pragma unroll
      for (int nf = 0; nf < 4; ++nf) {
        const int col = ncol + nf * 16 + lr;
        const f32x4 v = acc[mf][nf];
        ushort4 pk;
        pk.x = f2bf(v[0]); pk.y = f2bf(v[1]);
        pk.z = f2bf(v[2]); pk.w = f2bf(v[3]);
        *(ushort4*)(Y + (size_t)(b * D_N + col) * S_N + s0) = pk;
      }
    }
  }
#undef STA
#undef STB
#undef LDA8
#undef LDB4
#undef MMAH
#undef BARR
#undef WAITL
#undef WAITV
}

// ---------------- flash attention (tri-buffered LDS K/V, counted vmcnt) ----
union AttnSMem {
  struct { u16 K[3][4096]; u16 V[3][4096]; } st;  // 48 KB, triple-buffered
  float ol[4][32 * 34];                           // epilogue transpose (17 KB)
};

__global__ __launch_bounds__(256, 3) void attn_fwd(const u16* __restrict__ Yq,
                                                   const u16* __restrict__ Yk,
                                                   const u16* __restrict__ Yv,
                                                   float* __restrict__ out) {
  // XCD-chunked work id: 1024 blocks, 8 XCDs, 128 consecutive ids per XCD
  const int bid = blockIdx.x;
  const int wid = (bid & 7) * 128 + (bid >> 3);
  const int qt = wid & 7, bh = wid >> 3;
  const int b = bh >> 4, h = bh & 15;
  const int t = threadIdx.x, w = t >> 6, l = t & 63;
  const int ln = l & 31, hi = l >> 5;

  __shared__ AttnSMem sm;

  const int qbase = qt * 128 + w * 32;

  // ---- staging constants (pre-swizzled global source, rule 21) ----
  const int row0 = w * 8 + (l >> 3);
  const int srcoff = (((l & 7) ^ ((l >> 3) & 7)) << 3);
  const u16* kS0 = Yk + ((size_t)(b * S_N + row0) * D_N + h * HD_N + srcoff);
  const u16* vS0 = Yv + ((size_t)(b * D_N + h * HD_N + row0) * S_N + srcoff);

#define STAGE(buf, tt)                                                        \
  do {                                                                        \
    const u16* ka_ = kS0 + (size_t)(tt) * 64 * D_N;                           \
    const u16* va_ = vS0 + (tt) * 64;                                         \
    gl_lds16(ka_, sm.st.K[buf] + w * 512);                                    \
    gl_lds16(ka_ + (size_t)32 * D_N, sm.st.K[buf] + 2048 + w * 512);          \
    gl_lds16(va_, sm.st.V[buf] + w * 512);                                    \
    gl_lds16(va_ + (size_t)32 * S_N, sm.st.V[buf] + 2048 + w * 512);          \
  } while (0)

  // Q loads FIRST (oldest in the vm queue)
  bfrag qf[4];
  {
    const u16* qp = Yq + ((size_t)(b * S_N + qbase + ln) * D_N + h * HD_N + hi * 8);
#pragma unroll
    for (int c = 0; c < 4; ++c) qf[c] = *(const bfrag*)(qp + c * 16);
  }

  // prologue: stage tiles 0 and 1
  STAGE(0, 0);
  STAGE(1, 1);

  int kcol[4];
#pragma unroll
  for (int c = 0; c < 4; ++c)
    kcol[c] = (((c * 32 + hi * 16) ^ ((ln & 7) << 4)) >> 1);

  f32x16 o0, o1;
#pragma unroll
  for (int r = 0; r < 16; ++r) { o0[r] = 0.f; o1[r] = 0.f; }
  float m_r = -3.0e38f, l_r = 0.f;

  asm volatile("s_waitcnt vmcnt(4)" ::: "memory");
  __builtin_amdgcn_sched_barrier(0);
  __builtin_amdgcn_s_barrier();

  int rd = 0, sb = 2;  // read buffer kt%3; stage buffer (kt+2)%3
  for (int kt = 0; kt < 16; ++kt) {
    if (kt < 14) STAGE(sb, kt + 2);

    const u16* Kb = sm.st.K[rd];
    const u16* Vb = sm.st.V[rd];

    bfrag kf[8];
#pragma unroll
    for (int s2 = 0; s2 < 2; ++s2)
#pragma unroll
      for (int c = 0; c < 4; ++c)
        kf[s2 * 4 + c] = *(const bfrag*)(Kb + (s2 * 32 + ln) * 64 + kcol[c]);

    f32x16 sa, sbv;
#pragma unroll
    for (int r = 0; r < 16; ++r) { sa[r] = 0.f; sbv[r] = 0.f; }
    __builtin_amdgcn_s_setprio(1);
#pragma unroll
    for (int c = 0; c < 4; ++c) {
      sa = __builtin_amdgcn_mfma_f32_32x32x16_bf16(kf[c], qf[c], sa, 0, 0, 0);
      sbv = __builtin_amdgcn_mfma_f32_32x32x16_bf16(kf[4 + c], qf[c], sbv, 0, 0, 0);
    }
    __builtin_amdgcn_s_setprio(0);

    bfrag vf[8];
#pragma unroll
    for (int hf = 0; hf < 2; ++hf)
#pragma unroll
      for (int c = 0; c < 4; ++c)
        vf[hf * 4 + c] = *(const bfrag*)(Vb + (hf * 32 + ln) * 64 + kcol[c]);

    // ---- online softmax, in-lane, tree reductions ----
    float t16[16];
#pragma unroll
    for (int r = 0; r < 16; ++r) t16[r] = fmaxf(sa[r], sbv[r]);
    float t8[8];
#pragma unroll
    for (int r = 0; r < 8; ++r) t8[r] = fmaxf(t16[r], t16[r + 8]);
    float t4[4];
#pragma unroll
    for (int r = 0; r < 4; ++r) t4[r] = fmaxf(t8[r], t8[r + 4]);
    float pmax = fmaxf(fmaxf(t4[0], t4[1]), fmaxf(t4[2], t4[3]));
    pmax = xhalf_max(pmax);

    if (__any(pmax > m_r + 8.f)) {  // defer-max (T13)
      const float mnew = fmaxf(m_r, pmax);
      const float corr = exp2f(m_r - mnew);
#pragma unroll
      for (int r = 0; r < 16; ++r) { o0[r] *= corr; o1[r] *= corr; }
      l_r *= corr;
      m_r = mnew;
    }

#pragma unroll
    for (int r = 0; r < 16; ++r) sa[r] = exp2f(sa[r] - m_r);
#pragma unroll
    for (int r = 0; r < 16; ++r) sbv[r] = exp2f(sbv[r] - m_r);
    float s16[16];
#pragma unroll
    for (int r = 0; r < 16; ++r) s16[r] = sa[r] + sbv[r];
    float s8[8];
#pragma unroll
    for (int r = 0; r < 8; ++r) s8[r] = s16[r] + s16[r + 8];
    float s4[4];
#pragma unroll
    for (int r = 0; r < 4; ++r) s4[r] = s8[r] + s8[r + 4];
    float rsum = (s4[0] + s4[1]) + (s4[2] + s4[3]);
    l_r += xhalf_add(rsum);

    // ---- pack P to bf16 (cvt_pk + permlane32_swap) + PV ----
    __builtin_amdgcn_s_setprio(1);
#pragma unroll
    for (int c = 0; c < 4; ++c) {
      const int bs = (c & 1) * 8;
      float p0, p1, p2, p3, p4, p5, p6, p7;
      if (c < 2) {
        p0 = sa[bs + 0]; p1 = sa[bs + 1]; p2 = sa[bs + 2]; p3 = sa[bs + 3];
        p4 = sa[bs + 4]; p5 = sa[bs + 5]; p6 = sa[bs + 6]; p7 = sa[bs + 7];
      } else {
        p0 = sbv[bs + 0]; p1 = sbv[bs + 1]; p2 = sbv[bs + 2]; p3 = sbv[bs + 3];
        p4 = sbv[bs + 4]; p5 = sbv[bs + 5]; p6 = sbv[bs + 6]; p7 = sbv[bs + 7];
      }
      const u32 x1 = cvtpk(p0, p1), x2 = cvtpk(p2, p3);
      const u32 y1 = cvtpk(p4, p5), y2 = cvtpk(p6, p7);
      const u32x2 s1 = pl32swap(x1, y1);
      const u32x2 s2 = pl32swap(x2, y2);
      union { u32 u[4]; bfrag v; } pu;
      pu.u[0] = s1[0]; pu.u[1] = s2[0]; pu.u[2] = s1[1]; pu.u[3] = s2[1];
      o0 = __builtin_amdgcn_mfma_f32_32x32x16_bf16(vf[c], pu.v, o0, 0, 0, 0);
      o1 = __builtin_amdgcn_mfma_f32_32x32x16_bf16(vf[4 + c], pu.v, o1, 0, 0, 0);
    }
    __builtin_amdgcn_s_setprio(0);

    if (kt < 14) {
      asm volatile("s_waitcnt vmcnt(4)" ::: "memory");
    } else {
      asm volatile("s_waitcnt vmcnt(0)" ::: "memory");
    }
    __builtin_amdgcn_sched_barrier(0);
    __builtin_amdgcn_s_barrier();

    rd = (rd == 2) ? 0 : rd + 1;
    sb = (sb == 2) ? 0 : sb + 1;
  }

  // ---- epilogue: normalize, transpose O^T -> O via LDS (2 half-passes) ----
  const float inv = 1.f / l_r;
  float* ow = sm.ol[w];
  const int qr = l >> 1, ch = l & 1;
  const float* rp = ow + qr * 34 + ch * 16;
  float* op = out + ((size_t)(b * S_N + qbase + qr) * D_N + h * HD_N + ch * 16);

#pragma unroll
  for (int g = 0; g < 4; ++g) {
    f32x4 v;
#pragma unroll
    for (int j = 0; j < 4; ++j) v[j] = o0[g * 4 + j] * inv;
    *(f32x4*)(ow + ln * 34 + g * 8 + hi * 4) = v;
  }
  asm volatile("s_waitcnt lgkmcnt(0)" ::: "memory");
  __builtin_amdgcn_sched_barrier(0);
#pragma unroll
  for (int j = 0; j < 4; ++j)
    *(f32x4*)(op + j * 4) = *(const f32x4*)(rp + j * 4);
  asm volatile("s_waitcnt lgkmcnt(0)" ::: "memory");
  __builtin_amdgcn_sched_barrier(0);

#pragma unroll
  for (int g = 0; g < 4; ++g) {
    f32x4 v;
#pragma unroll
    for (int j = 0; j < 4; ++j) v[j] = o1[g * 4 + j] * inv;
    *(f32x4*)(ow + ln * 34 + g * 8 + hi * 4) = v;
  }
  asm volatile("s_waitcnt lgkmcnt(0)" ::: "memory");
  __builtin_amdgcn_sched_barrier(0);
#pragma unroll
  for (int j = 0; j < 4; ++j)
    *(f32x4*)(op + 32 + j * 4) = *(const f32x4*)(rp + j * 4);
#undef STAGE
}

// ---------------------------------------------------------------------------
extern "C" void kernel_launch(void* const* d_in, const int* in_sizes, int n_in,
                              void* d_out, int out_size, void* d_ws, size_t ws_size,
                              hipStream_t stream) {
  const float* Qs = (const float*)d_in[0];
  const float* Ks = (const float*)d_in[1];
  const float* Vs = (const float*)d_in[2];
  const float* WQ = (const float*)d_in[3];
  const float* WK = (const float*)d_in[4];
  const float* WV = (const float*)d_in[5];
  if (ws_size < 106954752ull) return;  // need ~102 MiB scratch

  u16* Xbf = (u16*)d_ws;             // 3 * 8,388,608
  u16* Wbf = Xbf + 25165824;         // 3 * 1,048,576
  u16* Ybf = Wbf + 3145728;          // 3 * 8,388,608
  float* out = (float*)d_out;

  cvt3<<<dim3(8192, 3), 256, 0, stream>>>(Qs, Ks, Vs, Xbf, Xbf + 8388608,
                                          Xbf + 16777216, 2097152);
  cvt3<<<dim3(1024, 3), 256, 0, stream>>>(WQ, WK, WV, Wbf, Wbf + 1048576,
                                          Wbf + 2097152, 262144);
  gemm_qkv<<<dim3(768), 512, 0, stream>>>(Xbf, Wbf, Ybf);
  attn_fwd<<<dim3(1024), 256, 0, stream>>>(Ybf, Ybf + 8388608, Ybf + 16777216, out);
}

// Round 8
// 142.749 us; speedup vs baseline: 1.9666x; 1.1204x over previous
//
#include <hip/hip_runtime.h>
#include <stdint.h>

// ---------------------------------------------------------------------------
// SelfAttention: B=8,S=1024,D=1024,H=16,HD=64
//   Y{q,k,v} = X @ W^T (bf16 MFMA, fp32 acc), then flash attention.
//   Q epilogue folds scale 0.125 * log2(e) so softmax uses exp2.
//   V is written transposed [B][D][S] so PV A-fragments read V^T rows.
// Round 8:
//  - cvt3 ELIMINATED: gemm reads fp32 X/W directly and converts in its
//    staging path (global_load float4 -> v_cvt_pk_bf16_f32 -> swizzled
//    ds_write_b128). 2-buffer LDS (96 KB), loads for kt+2 issued during kt,
//    vmcnt(0) at top of kt+1 (one tile of latency cover; A panels are
//    L2-resident via XCD chunking). Saves ~105 MB HBM traffic + a serial
//    ~28us dispatch.
//  - attn: exp2f -> raw v_exp_f32 (OCML exp2 carries a denormal-guard
//    sequence ~5 VALU ops; our args never need it).
// ws layout: Ybf only: 3 * 8192*1024 bf16 = 50,331,648 bytes.
// ---------------------------------------------------------------------------

#define B_N 8
#define S_N 1024
#define D_N 1024
#define H_N 16
#define HD_N 64
#define M_N (B_N * S_N) /* 8192 */

typedef __bf16 bfrag __attribute__((ext_vector_type(8)));
typedef float f32x4 __attribute__((ext_vector_type(4)));
typedef float f32x16 __attribute__((ext_vector_type(16)));
typedef unsigned int u32;
typedef u32 u32x2 __attribute__((ext_vector_type(2)));
typedef u32 u32x4 __attribute__((ext_vector_type(4)));
typedef unsigned short u16;

__device__ __forceinline__ u16 f2bf(float f) {  // RNE fp32 -> bf16 bits
  uint32_t u = __float_as_uint(f);
  u += 0x7FFFu + ((u >> 16) & 1u);
  return (u16)(u >> 16);
}

__device__ __forceinline__ void gl_lds16(const void* g, void* l) {
  __builtin_amdgcn_global_load_lds(
      (const __attribute__((address_space(1))) uint32_t*)g,
      (__attribute__((address_space(3))) uint32_t*)l, 16, 0, 0);
}

__device__ __forceinline__ u32 cvtpk(float lo, float hi) {
  u32 r;
  asm("v_cvt_pk_bf16_f32 %0, %1, %2" : "=v"(r) : "v"(lo), "v"(hi));
  return r;
}

__device__ __forceinline__ float exp2r(float x) {  // raw v_exp_f32
#if __has_builtin(__builtin_amdgcn_exp2f)
  return __builtin_amdgcn_exp2f(x);
#else
  float r;
  asm("v_exp_f32 %0, %1" : "=v"(r) : "v"(x));
  return r;
#endif
}

__device__ __forceinline__ u32x2 pl32swap(u32 a, u32 b) {
#if __has_builtin(__builtin_amdgcn_permlane32_swap)
  return __builtin_amdgcn_permlane32_swap(a, b, false, false);
#else
  u32 sa = (u32)__shfl_xor((int)a, 32, 64), sb = (u32)__shfl_xor((int)b, 32, 64);
  const bool hi = (threadIdx.x & 32) != 0;
  u32x2 r;
  r[0] = hi ? sb : a;
  r[1] = hi ? b : sa;
  return r;
#endif
}

__device__ __forceinline__ float xhalf_max(float v) {
  u32x2 r = pl32swap(__float_as_uint(v), __float_as_uint(v));
  return fmaxf(__uint_as_float(r[0]), __uint_as_float(r[1]));
}
__device__ __forceinline__ float xhalf_add(float v) {
  u32x2 r = pl32swap(__float_as_uint(v), __float_as_uint(v));
  return __uint_as_float(r[0]) + __uint_as_float(r[1]);
}

// ---------------- fused projection GEMM: Y = bf16(X) @ bf16(W)^T -----------
// fp32 inputs, conversion fused into reg-staging. 256x128 tiles, 768 blocks
// = 3 exact rounds, 8 waves 4Mx2N, 2-buffer LDS (96 KB).
// Pipeline: loads(kt+2) issued during kt; vmcnt(0)+WRITET(kt+1) at top of
// kt+1; writes drained by the pre-MFMA lgkmcnt(0); one barrier per tile.
__global__ __launch_bounds__(512, 1) void gemm_qkv(
    const float* __restrict__ Qs, const float* __restrict__ Ks,
    const float* __restrict__ Vs, const float* __restrict__ WQ,
    const float* __restrict__ WK, const float* __restrict__ WV,
    u16* __restrict__ Ybf) {
  const int bid = blockIdx.x;
  const int wid = (bid & 7) * 96 + (bid >> 3);  // bijective: 768 % 8 == 0
  const int mat = wid >> 8;                     // 256 tiles per matrix
  const int rem = wid & 255;
  const int m0 = (rem >> 3) * 256;
  const int n0 = (rem & 7) * 128;

  const float* A = mat == 0 ? Qs : (mat == 1 ? Ks : Vs);
  const float* Bw = mat == 0 ? WQ : (mat == 1 ? WK : WV);
  u16* Y = Ybf + (size_t)mat * (M_N * D_N);

  __shared__ u16 Ast[2][4][4096];  // [buf][chunk: 64 rows][64x64], 64 KB
  __shared__ u16 Bst[2][2][4096];  // [buf][chunk: 64 cols][64x64], 32 KB

  const int t = threadIdx.x;
  const int w = t >> 6, l = t & 63;
  const int lr = l & 15, lg = l >> 4;
  const int wm = w >> 1, wn = w & 1;

  // staging: thread t owns row t>>3, 8-elem slot t&7 of each 64x64 chunk.
  const float* aSrc = A + (size_t)(m0 + (t >> 3)) * D_N + (t & 7) * 8;
  const float* bSrc = Bw + (size_t)(n0 + (t >> 3)) * D_N + (t & 7) * 8;
  // swizzled ds_write dest (u16 units within a chunk)
  const int dst8 = (t >> 3) * 64 + ((((t & 7) ^ ((t >> 3) & 7))) << 3);

  // swizzled ds_read column offsets (u16 units)
  const int asw = (lr & 7) << 3;
  const int koff0 = (lg * 8) ^ asw;
  const int koff1 = (32 + lg * 8) ^ asw;

  float4 ra[4][2], rw[2][2];

#define LOADT(tt)                                                             \
  do {                                                                        \
    _Pragma("unroll") for (int c_ = 0; c_ < 4; ++c_) {                        \
      ra[c_][0] = *(const float4*)(aSrc + (size_t)(c_ * 64) * D_N + (tt)*64); \
      ra[c_][1] =                                                             \
          *(const float4*)(aSrc + (size_t)(c_ * 64) * D_N + (tt)*64 + 4);     \
    }                                                                         \
    _Pragma("unroll") for (int c_ = 0; c_ < 2; ++c_) {                        \
      rw[c_][0] = *(const float4*)(bSrc + (size_t)(c_ * 64) * D_N + (tt)*64); \
      rw[c_][1] =                                                             \
          *(const float4*)(bSrc + (size_t)(c_ * 64) * D_N + (tt)*64 + 4);     \
    }                                                                         \
  } while (0)
#define WRITET(buf)                                                           \
  do {                                                                        \
    _Pragma("unroll") for (int c_ = 0; c_ < 4; ++c_) {                        \
      u32x4 pk_;                                                              \
      pk_[0] = cvtpk(ra[c_][0].x, ra[c_][0].y);                               \
      pk_[1] = cvtpk(ra[c_][0].z, ra[c_][0].w);                               \
      pk_[2] = cvtpk(ra[c_][1].x, ra[c_][1].y);                               \
      pk_[3] = cvtpk(ra[c_][1].z, ra[c_][1].w);                               \
      *(u32x4*)(&Ast[buf][c_][dst8]) = pk_;                                   \
    }                                                                         \
    _Pragma("unroll") for (int c_ = 0; c_ < 2; ++c_) {                        \
      u32x4 pk_;                                                              \
      pk_[0] = cvtpk(rw[c_][0].x, rw[c_][0].y);                               \
      pk_[1] = cvtpk(rw[c_][0].z, rw[c_][0].w);                               \
      pk_[2] = cvtpk(rw[c_][1].x, rw[c_][1].y);                               \
      pk_[3] = cvtpk(rw[c_][1].z, rw[c_][1].w);                               \
      *(u32x4*)(&Bst[buf][c_][dst8]) = pk_;                                   \
    }                                                                         \
  } while (0)
#define LDA8(AR, buf)                                                         \
  do {                                                                        \
    const u16* p_ = &Ast[buf][wm][lr * 64];                                   \
    _Pragma("unroll") for (int mf_ = 0; mf_ < 4; ++mf_) {                     \
      AR[mf_][0] = *(const bfrag*)(p_ + mf_ * 1024 + koff0);                  \
      AR[mf_][1] = *(const bfrag*)(p_ + mf_ * 1024 + koff1);                  \
    }                                                                         \
  } while (0)
#define LDB4(BR, buf, h)                                                      \
  do {                                                                        \
    const u16* p_ = &Bst[buf][wn][((h)*32 + lr) * 64];                        \
    BR[0][0] = *(const bfrag*)(p_ + koff0);                                   \
    BR[0][1] = *(const bfrag*)(p_ + koff1);                                   \
    BR[1][0] = *(const bfrag*)(p_ + 1024 + koff0);                            \
    BR[1][1] = *(const bfrag*)(p_ + 1024 + koff1);                            \
  } while (0)
#define MMAH(h, AR, BR)                                                       \
  do {                                                                        \
    __builtin_amdgcn_s_setprio(1);                                            \
    _Pragma("unroll") for (int mf_ = 0; mf_ < 4; ++mf_)                       \
    _Pragma("unroll") for (int j_ = 0; j_ < 2; ++j_)                          \
    _Pragma("unroll") for (int kk_ = 0; kk_ < 2; ++kk_)                       \
      acc[mf_][(h)*2 + j_] = __builtin_amdgcn_mfma_f32_16x16x32_bf16(         \
          AR[mf_][kk_], BR[j_][kk_], acc[mf_][(h)*2 + j_], 0, 0, 0);          \
    __builtin_amdgcn_s_setprio(0);                                            \
  } while (0)
#define BARR()                                                                \
  __builtin_amdgcn_s_barrier();                                               \
  __builtin_amdgcn_sched_barrier(0)
#define WAITL()                                                               \
  asm volatile("s_waitcnt lgkmcnt(0)" ::: "memory");                          \
  __builtin_amdgcn_sched_barrier(0)
#define WAITV0()                                                              \
  asm volatile("s_waitcnt vmcnt(0)" ::: "memory");                            \
  __builtin_amdgcn_sched_barrier(0)

  f32x4 acc[4][4];
#pragma unroll
  for (int i = 0; i < 4; ++i)
#pragma unroll
    for (int j = 0; j < 4; ++j) acc[i][j] = (f32x4){0.f, 0.f, 0.f, 0.f};

  // prologue: tile0 load->write; tile1 loads in flight
  LOADT(0);
  WAITV0();
  WRITET(0);
  LOADT(1);
  WAITL();
  BARR();

  for (int kt = 0; kt < 16; ++kt) {
    const int cb = kt & 1;
    bfrag a[4][2], b[2][2];
    LDA8(a, cb);
    LDB4(b, cb, 0);
    if (kt < 15) {
      WAITV0();          // tile kt+1 loads (issued during kt-1) done
      WRITET(cb ^ 1);    // publish kt+1 into the buffer freed at end of kt-1
      if (kt < 14) LOADT(kt + 2);
    }
    WAITL();             // frag reads + ds_writes drained
    MMAH(0, a, b);
    LDB4(b, cb, 1);
    WAITL();
    MMAH(1, a, b);
    BARR();              // publish writes; free buffer cb for kt+2's write
  }

  // ---- epilogue ----
  const float alpha = (mat == 0) ? 0.18033688011112042f : 1.0f;
  const int mrow = m0 + wm * 64;
  const int ncol = n0 + wn * 64;
  if (mat < 2) {
#pragma unroll
    for (int mf = 0; mf < 4; ++mf) {
      const int row0 = mrow + mf * 16 + lg * 4;
#pragma unroll
      for (int nf = 0; nf < 4; ++nf) {
        const int col = ncol + nf * 16 + lr;
#pragma unroll
        for (int r = 0; r < 4; ++r)
          Y[(size_t)(row0 + r) * D_N + col] = f2bf(acc[mf][nf][r] * alpha);
      }
    }
  } else {
    const int b = m0 >> 10;
#pragma unroll
    for (int mf = 0; mf < 4; ++mf) {
      const int s0 = (m0 & 1023) + wm * 64 + mf * 16 + lg * 4;
#pragma unroll
      for (int nf = 0; nf < 4; ++nf) {
        const int col = ncol + nf * 16 + lr;
        const f32x4 v = acc[mf][nf];
        ushort4 pk;
        pk.x = f2bf(v[0]); pk.y = f2bf(v[1]);
        pk.z = f2bf(v[2]); pk.w = f2bf(v[3]);
        *(ushort4*)(Y + (size_t)(b * D_N + col) * S_N + s0) = pk;
      }
    }
  }
#undef LOADT
#undef WRITET
#undef LDA8
#undef LDB4
#undef MMAH
#undef BARR
#undef WAITL
#undef WAITV0
}

// ---------------- flash attention (tri-buffered LDS K/V, counted vmcnt) ----
union AttnSMem {
  struct { u16 K[3][4096]; u16 V[3][4096]; } st;  // 48 KB, triple-buffered
  float ol[4][32 * 34];                           // epilogue transpose (17 KB)
};

__global__ __launch_bounds__(256, 3) void attn_fwd(const u16* __restrict__ Yq,
                                                   const u16* __restrict__ Yk,
                                                   const u16* __restrict__ Yv,
                                                   float* __restrict__ out) {
  // XCD-chunked work id: 1024 blocks, 8 XCDs, 128 consecutive ids per XCD
  const int bid = blockIdx.x;
  const int wid = (bid & 7) * 128 + (bid >> 3);
  const int qt = wid & 7, bh = wid >> 3;
  const int b = bh >> 4, h = bh & 15;
  const int t = threadIdx.x, w = t >> 6, l = t & 63;
  const int ln = l & 31, hi = l >> 5;

  __shared__ AttnSMem sm;

  const int qbase = qt * 128 + w * 32;

  // ---- staging constants (pre-swizzled global source, rule 21) ----
  const int row0 = w * 8 + (l >> 3);
  const int srcoff = (((l & 7) ^ ((l >> 3) & 7)) << 3);
  const u16* kS0 = Yk + ((size_t)(b * S_N + row0) * D_N + h * HD_N + srcoff);
  const u16* vS0 = Yv + ((size_t)(b * D_N + h * HD_N + row0) * S_N + srcoff);

#define STAGE(buf, tt)                                                        \
  do {                                                                        \
    const u16* ka_ = kS0 + (size_t)(tt) * 64 * D_N;                           \
    const u16* va_ = vS0 + (tt) * 64;                                         \
    gl_lds16(ka_, sm.st.K[buf] + w * 512);                                    \
    gl_lds16(ka_ + (size_t)32 * D_N, sm.st.K[buf] + 2048 + w * 512);          \
    gl_lds16(va_, sm.st.V[buf] + w * 512);                                    \
    gl_lds16(va_ + (size_t)32 * S_N, sm.st.V[buf] + 2048 + w * 512);          \
  } while (0)

  // Q loads FIRST (oldest in the vm queue)
  bfrag qf[4];
  {
    const u16* qp = Yq + ((size_t)(b * S_N + qbase + ln) * D_N + h * HD_N + hi * 8);
#pragma unroll
    for (int c = 0; c < 4; ++c) qf[c] = *(const bfrag*)(qp + c * 16);
  }

  // prologue: stage tiles 0 and 1
  STAGE(0, 0);
  STAGE(1, 1);

  int kcol[4];
#pragma unroll
  for (int c = 0; c < 4; ++c)
    kcol[c] = (((c * 32 + hi * 16) ^ ((ln & 7) << 4)) >> 1);

  f32x16 o0, o1;
#pragma unroll
  for (int r = 0; r < 16; ++r) { o0[r] = 0.f; o1[r] = 0.f; }
  float m_r = -3.0e38f, l_r = 0.f;

  asm volatile("s_waitcnt vmcnt(4)" ::: "memory");
  __builtin_amdgcn_sched_barrier(0);
  __builtin_amdgcn_s_barrier();

  int rd = 0, sb = 2;  // read buffer kt%3; stage buffer (kt+2)%3
  for (int kt = 0; kt < 16; ++kt) {
    if (kt < 14) STAGE(sb, kt + 2);

    const u16* Kb = sm.st.K[rd];
    const u16* Vb = sm.st.V[rd];

    bfrag kf[8];
#pragma unroll
    for (int s2 = 0; s2 < 2; ++s2)
#pragma unroll
      for (int c = 0; c < 4; ++c)
        kf[s2 * 4 + c] = *(const bfrag*)(Kb + (s2 * 32 + ln) * 64 + kcol[c]);

    f32x16 sa, sbv;
#pragma unroll
    for (int r = 0; r < 16; ++r) { sa[r] = 0.f; sbv[r] = 0.f; }
    __builtin_amdgcn_s_setprio(1);
#pragma unroll
    for (int c = 0; c < 4; ++c) {
      sa = __builtin_amdgcn_mfma_f32_32x32x16_bf16(kf[c], qf[c], sa, 0, 0, 0);
      sbv = __builtin_amdgcn_mfma_f32_32x32x16_bf16(kf[4 + c], qf[c], sbv, 0, 0, 0);
    }
    __builtin_amdgcn_s_setprio(0);

    bfrag vf[8];
#pragma unroll
    for (int hf = 0; hf < 2; ++hf)
#pragma unroll
      for (int c = 0; c < 4; ++c)
        vf[hf * 4 + c] = *(const bfrag*)(Vb + (hf * 32 + ln) * 64 + kcol[c]);

    // ---- online softmax, in-lane, tree reductions ----
    float t16[16];
#pragma unroll
    for (int r = 0; r < 16; ++r) t16[r] = fmaxf(sa[r], sbv[r]);
    float t8[8];
#pragma unroll
    for (int r = 0; r < 8; ++r) t8[r] = fmaxf(t16[r], t16[r + 8]);
    float t4[4];
#pragma unroll
    for (int r = 0; r < 4; ++r) t4[r] = fmaxf(t8[r], t8[r + 4]);
    float pmax = fmaxf(fmaxf(t4[0], t4[1]), fmaxf(t4[2], t4[3]));
    pmax = xhalf_max(pmax);

    if (__any(pmax > m_r + 8.f)) {  // defer-max (T13)
      const float mnew = fmaxf(m_r, pmax);
      const float corr = exp2r(m_r - mnew);
#pragma unroll
      for (int r = 0; r < 16; ++r) { o0[r] *= corr; o1[r] *= corr; }
      l_r *= corr;
      m_r = mnew;
    }

#pragma unroll
    for (int r = 0; r < 16; ++r) sa[r] = exp2r(sa[r] - m_r);
#pragma unroll
    for (int r = 0; r < 16; ++r) sbv[r] = exp2r(sbv[r] - m_r);
    float s16[16];
#pragma unroll
    for (int r = 0; r < 16; ++r) s16[r] = sa[r] + sbv[r];
    float s8[8];
#pragma unroll
    for (int r = 0; r < 8; ++r) s8[r] = s16[r] + s16[r + 8];
    float s4[4];
#pragma unroll
    for (int r = 0; r < 4; ++r) s4[r] = s8[r] + s8[r + 4];
    float rsum = (s4[0] + s4[1]) + (s4[2] + s4[3]);
    l_r += xhalf_add(rsum);

    // ---- pack P to bf16 (cvt_pk + permlane32_swap) + PV ----
    __builtin_amdgcn_s_setprio(1);
#pragma unroll
    for (int c = 0; c < 4; ++c) {
      const int bs = (c & 1) * 8;
      float p0, p1, p2, p3, p4, p5, p6, p7;
      if (c < 2) {
        p0 = sa[bs + 0]; p1 = sa[bs + 1]; p2 = sa[bs + 2]; p3 = sa[bs + 3];
        p4 = sa[bs + 4]; p5 = sa[bs + 5]; p6 = sa[bs + 6]; p7 = sa[bs + 7];
      } else {
        p0 = sbv[bs + 0]; p1 = sbv[bs + 1]; p2 = sbv[bs + 2]; p3 = sbv[bs + 3];
        p4 = sbv[bs + 4]; p5 = sbv[bs + 5]; p6 = sbv[bs + 6]; p7 = sbv[bs + 7];
      }
      const u32 x1 = cvtpk(p0, p1), x2 = cvtpk(p2, p3);
      const u32 y1 = cvtpk(p4, p5), y2 = cvtpk(p6, p7);
      const u32x2 s1 = pl32swap(x1, y1);
      const u32x2 s2 = pl32swap(x2, y2);
      union { u32 u[4]; bfrag v; } pu;
      pu.u[0] = s1[0]; pu.u[1] = s2[0]; pu.u[2] = s1[1]; pu.u[3] = s2[1];
      o0 = __builtin_amdgcn_mfma_f32_32x32x16_bf16(vf[c], pu.v, o0, 0, 0, 0);
      o1 = __builtin_amdgcn_mfma_f32_32x32x16_bf16(vf[4 + c], pu.v, o1, 0, 0, 0);
    }
    __builtin_amdgcn_s_setprio(0);

    if (kt < 14) {
      asm volatile("s_waitcnt vmcnt(4)" ::: "memory");
    } else {
      asm volatile("s_waitcnt vmcnt(0)" ::: "memory");
    }
    __builtin_amdgcn_sched_barrier(0);
    __builtin_amdgcn_s_barrier();

    rd = (rd == 2) ? 0 : rd + 1;
    sb = (sb == 2) ? 0 : sb + 1;
  }

  // ---- epilogue: normalize, transpose O^T -> O via LDS (2 half-passes) ----
  const float inv = 1.f / l_r;
  float* ow = sm.ol[w];
  const int qr = l >> 1, ch = l & 1;
  const float* rp = ow + qr * 34 + ch * 16;
  float* op = out + ((size_t)(b * S_N + qbase + qr) * D_N + h * HD_N + ch * 16);

#pragma unroll
  for (int g = 0; g < 4; ++g) {
    f32x4 v;
#pragma unroll
    for (int j = 0; j < 4; ++j) v[j] = o0[g * 4 + j] * inv;
    *(f32x4*)(ow + ln * 34 + g * 8 + hi * 4) = v;
  }
  asm volatile("s_waitcnt lgkmcnt(0)" ::: "memory");
  __builtin_amdgcn_sched_barrier(0);
#pragma unroll
  for (int j = 0; j < 4; ++j)
    *(f32x4*)(op + j * 4) = *(const f32x4*)(rp + j * 4);
  asm volatile("s_waitcnt lgkmcnt(0)" ::: "memory");
  __builtin_amdgcn_sched_barrier(0);

#pragma unroll
  for (int g = 0; g < 4; ++g) {
    f32x4 v;
#pragma unroll
    for (int j = 0; j < 4; ++j) v[j] = o1[g * 4 + j] * inv;
    *(f32x4*)(ow + ln * 34 + g * 8 + hi * 4) = v;
  }
  asm volatile("s_waitcnt lgkmcnt(0)" ::: "memory");
  __builtin_amdgcn_sched_barrier(0);
#pragma unroll
  for (int j = 0; j < 4; ++j)
    *(f32x4*)(op + 32 + j * 4) = *(const f32x4*)(rp + j * 4);
#undef STAGE
}

// ---------------------------------------------------------------------------
extern "C" void kernel_launch(void* const* d_in, const int* in_sizes, int n_in,
                              void* d_out, int out_size, void* d_ws, size_t ws_size,
                              hipStream_t stream) {
  const float* Qs = (const float*)d_in[0];
  const float* Ks = (const float*)d_in[1];
  const float* Vs = (const float*)d_in[2];
  const float* WQ = (const float*)d_in[3];
  const float* WK = (const float*)d_in[4];
  const float* WV = (const float*)d_in[5];
  if (ws_size < 50331648ull) return;  // Ybf: 3 * 8192*1024 bf16

  u16* Ybf = (u16*)d_ws;
  float* out = (float*)d_out;

  gemm_qkv<<<dim3(768), 512, 0, stream>>>(Qs, Ks, Vs, WQ, WK, WV, Ybf);
  attn_fwd<<<dim3(1024), 256, 0, stream>>>(Ybf, Ybf + 8388608, Ybf + 16777216, out);
}